// Round 11
// baseline (338.941 us; speedup 1.0000x reference)
//
#include <hip/hip_runtime.h>
#include <math.h>

// Problem constants (from reference)
constexpr int N_NODES = 50000;
constexpr int N_EDGES = 800000;
constexpr int TOT_E   = N_EDGES + N_NODES;   // + self loops
constexpr int HCv     = 256;                 // H*C
constexpr int MAXD    = 256;                 // LDS logit-cache capacity per wave

// GEMM grid geometry
constexpr int GY        = (N_NODES + 127) / 128;  // 391 row-tiles
constexpr int GPX       = (GY + 7) / 8;           // 49 row-tiles per XCD
constexpr int GEMM_BLKS = 8 * GPX * 4;            // 1568 (tail guarded, XCD swizzle)

// merged scatter+gemm128 kernel geometry (gemm blocks first)
constexpr int SG_GEMM   = GY * 4;                 // 1564 gemm blocks (plain mapping)
constexpr int SC_BLKS   = (TOT_E + 255) / 256;    // 3321 scatter blocks
constexpr int SG_BLKS   = SG_GEMM + SC_BLKS;

// prep_k section sizes
constexpr int PREP_CVT   = (N_NODES * 128 / 4 + 255) / 256;   // 6250
constexpr int PREP_WT0   = 128;
constexpr int PREP_WT1   = 256;
constexpr int PREP_DEG   = (TOT_E + 255) / 256;               // 3321
constexpr int PREP_ZERO  = (N_NODES * 8 / 4 + 255) / 256;     // 391 (both layers' a_s/a_d)
constexpr int PREP_BLKS  = PREP_CVT + PREP_WT0 + PREP_WT1 + PREP_DEG + PREP_ZERO;

typedef __attribute__((ext_vector_type(8))) short bf16x8;
typedef __attribute__((ext_vector_type(4))) float f32x4;
typedef __attribute__((ext_vector_type(2))) float f32x2;

// ---- bf16 helpers (manual RNE, deterministic) ----
__device__ __forceinline__ unsigned short f2bf(float f) {
    unsigned int u = __float_as_uint(f);
    unsigned int r = (u + 0x7fffu + ((u >> 16) & 1u)) >> 16;
    return (unsigned short)r;
}
__device__ __forceinline__ unsigned int f2bf_pack(float lo, float hi) {
    return (unsigned int)f2bf(lo) | ((unsigned int)f2bf(hi) << 16);
}
__device__ __forceinline__ float bf2f_lo(unsigned int packed) {
    return __uint_as_float(packed << 16);
}
__device__ __forceinline__ float bf2f_hi(unsigned int packed) {
    return __uint_as_float(packed & 0xffff0000u);
}

// 8 bf16 channels += alpha * row-fragment, packed f32x2
__device__ __forceinline__ void fma_row8_pk(const uint4 h, f32x2 al, f32x2* a2) {
    f32x2 p;
    p.x = bf2f_lo(h.x); p.y = bf2f_hi(h.x);
    a2[0] = __builtin_elementwise_fma(p, al, a2[0]);
    p.x = bf2f_lo(h.y); p.y = bf2f_hi(h.y);
    a2[1] = __builtin_elementwise_fma(p, al, a2[1]);
    p.x = bf2f_lo(h.z); p.y = bf2f_hi(h.z);
    a2[2] = __builtin_elementwise_fma(p, al, a2[2]);
    p.x = bf2f_lo(h.w); p.y = bf2f_hi(h.w);
    a2[3] = __builtin_elementwise_fma(p, al, a2[3]);
}

// ---------------- fused prep: cvt x, transpose W0/W1, count degrees, zero a_s/a_d x2 ----

__global__ __launch_bounds__(256) void prep_k(const float* __restrict__ x,
                                              unsigned short* __restrict__ xb,
                                              const float* __restrict__ W0,
                                              unsigned short* __restrict__ WT0,
                                              const float* __restrict__ W1,
                                              unsigned short* __restrict__ WT1,
                                              const int* __restrict__ ei,
                                              int* __restrict__ deg,
                                              float* __restrict__ a_sd) {
    int b = blockIdx.x;
    if (b < PREP_CVT) {                       // x -> bf16 (float4 quads)
        int i = b * 256 + threadIdx.x;
        if (i < N_NODES * 128 / 4) {
            float4 v = *reinterpret_cast<const float4*>(x + (size_t)i * 4);
            ushort4 o;
            o.x = f2bf(v.x); o.y = f2bf(v.y); o.z = f2bf(v.z); o.w = f2bf(v.w);
            *reinterpret_cast<ushort4*>(xb + (size_t)i * 4) = o;
        }
        return;
    }
    b -= PREP_CVT;
    if (b < PREP_WT0) {                       // WT0[n][k] = bf16(W0[k][n]), K=128
        int idx = b * 256 + threadIdx.x;
        int k = idx >> 8, n = idx & 255;
        WT0[(size_t)n * 128 + k] = f2bf(W0[idx]);
        return;
    }
    b -= PREP_WT0;
    if (b < PREP_WT1) {                       // WT1[n][k] = bf16(W1[k][n]), K=256
        int idx = b * 256 + threadIdx.x;
        int k = idx >> 8, n = idx & 255;
        WT1[(size_t)n * 256 + k] = f2bf(W1[idx]);
        return;
    }
    b -= PREP_WT1;
    if (b < PREP_DEG) {                       // degree count
        int e = b * 256 + threadIdx.x;
        if (e < TOT_E) {
            int dst = (e < N_EDGES) ? ei[N_EDGES + e] : (e - N_EDGES);
            atomicAdd(&deg[dst], 1);
        }
        return;
    }
    b -= PREP_DEG;
    {                                         // zero a_s/a_d for BOTH layers (N*8 floats)
        int i = b * 256 + threadIdx.x;
        if (i < N_NODES * 2)
            *reinterpret_cast<float4*>(a_sd + (size_t)i * 4) = make_float4(0, 0, 0, 0);
    }
}

// ---------------- CSR build ----------------

__global__ void offsets_k(const int* __restrict__ deg, int* __restrict__ start,
                          int* __restrict__ cursor, int* __restrict__ total) {
    int lane = threadIdx.x & 63;
    int node = blockIdx.x * blockDim.x + threadIdx.x;
    int d = (node < N_NODES) ? deg[node] : 0;
    int pre = d;
#pragma unroll
    for (int off = 1; off < 64; off <<= 1) {
        int v = __shfl_up(pre, off);
        if (lane >= off) pre += v;
    }
    int wtot = __shfl(pre, 63);
    int base = 0;
    if (lane == 63) base = atomicAdd(total, wtot);
    base = __shfl(base, 63);
    int my = base + pre - d;
    if (node < N_NODES) { start[node] = my; cursor[node] = my; }
}

// ---------------- GEMM body (shared device function) ----------------

template <int K>
__device__ __forceinline__ void gemm_body(int gy, int kx,
        const unsigned short* __restrict__ A, const unsigned short* __restrict__ BT,
        unsigned short* __restrict__ h16,
        const float* __restrict__ att_src, const float* __restrict__ att_dst,
        float* __restrict__ a_s, float* __restrict__ a_d, int M) {
    const int lane = threadIdx.x & 63;
    const int wv = threadIdx.x >> 6;
    const int lm = lane & 15;
    const int g8 = (lane >> 4) * 8;
    const int row0 = gy * 128 + wv * 32;
    const int n0 = kx * 64;

    int ra0 = row0 + lm;       if (ra0 >= M) ra0 = M - 1;
    int ra1 = row0 + 16 + lm;  if (ra1 >= M) ra1 = M - 1;
    const unsigned short* pa0 = A + (size_t)ra0 * K + g8;
    const unsigned short* pa1 = A + (size_t)ra1 * K + g8;
    const unsigned short* pb  = BT + (size_t)(n0 + lm) * K + g8;

    f32x4 acc[2][4] = {};
#pragma unroll
    for (int kt = 0; kt < K; kt += 32) {
        bf16x8 a0 = *reinterpret_cast<const bf16x8*>(pa0 + kt);
        bf16x8 a1 = *reinterpret_cast<const bf16x8*>(pa1 + kt);
        bf16x8 b0 = *reinterpret_cast<const bf16x8*>(pb + kt);
        bf16x8 b1 = *reinterpret_cast<const bf16x8*>(pb + 16 * K + kt);
        bf16x8 b2 = *reinterpret_cast<const bf16x8*>(pb + 32 * K + kt);
        bf16x8 b3 = *reinterpret_cast<const bf16x8*>(pb + 48 * K + kt);
        acc[0][0] = __builtin_amdgcn_mfma_f32_16x16x32_bf16(a0, b0, acc[0][0], 0, 0, 0);
        acc[0][1] = __builtin_amdgcn_mfma_f32_16x16x32_bf16(a0, b1, acc[0][1], 0, 0, 0);
        acc[0][2] = __builtin_amdgcn_mfma_f32_16x16x32_bf16(a0, b2, acc[0][2], 0, 0, 0);
        acc[0][3] = __builtin_amdgcn_mfma_f32_16x16x32_bf16(a0, b3, acc[0][3], 0, 0, 0);
        acc[1][0] = __builtin_amdgcn_mfma_f32_16x16x32_bf16(a1, b0, acc[1][0], 0, 0, 0);
        acc[1][1] = __builtin_amdgcn_mfma_f32_16x16x32_bf16(a1, b1, acc[1][1], 0, 0, 0);
        acc[1][2] = __builtin_amdgcn_mfma_f32_16x16x32_bf16(a1, b2, acc[1][2], 0, 0, 0);
        acc[1][3] = __builtin_amdgcn_mfma_f32_16x16x32_bf16(a1, b3, acc[1][3], 0, 0, 0);
    }

    float as_c[4], ad_c[4];
#pragma unroll
    for (int j = 0; j < 4; ++j) {
        int c = n0 + j * 16 + lm;
        as_c[j] = att_src[c];
        ad_c[j] = att_dst[c];
    }
    const int head = n0 >> 7;

#pragma unroll
    for (int i = 0; i < 2; ++i) {
        float ps[4] = {}, pd[4] = {};
#pragma unroll
        for (int j = 0; j < 4; ++j)
#pragma unroll
            for (int r = 0; r < 4; ++r) {
                ps[r] += acc[i][j][r] * as_c[j];
                pd[r] += acc[i][j][r] * ad_c[j];
            }
#pragma unroll
        for (int off = 1; off < 16; off <<= 1)
#pragma unroll
            for (int r = 0; r < 4; ++r) {
                ps[r] += __shfl_xor(ps[r], off);
                pd[r] += __shfl_xor(pd[r], off);
            }
        if (lm == 0) {
            int rb = row0 + i * 16 + (lane >> 4) * 4;
#pragma unroll
            for (int r = 0; r < 4; ++r) {
                if (rb + r < M) {
                    atomicAdd(&a_s[(rb + r) * 2 + head], ps[r]);
                    atomicAdd(&a_d[(rb + r) * 2 + head], pd[r]);
                }
            }
        }
#pragma unroll
        for (int j = 0; j < 4; ++j)
#pragma unroll
            for (int r = 0; r < 4; ++r) {
                int row = row0 + i * 16 + (lane >> 4) * 4 + r;
                if (row < M)
                    h16[(size_t)row * HCv + n0 + j * 16 + lm] = f2bf(acc[i][j][r]);
            }
    }
}

// ---------------- merged: gemm128 (layer 0) || CSR scatter ----------------
// gemm blocks first; the two phases touch disjoint buffers so they co-execute,
// hiding the scatter's random atomics under the GEMM.

__global__ __launch_bounds__(256) void sg_k(
        const unsigned short* __restrict__ A, const unsigned short* __restrict__ BT,
        unsigned short* __restrict__ h16,
        const float* __restrict__ att_src, const float* __restrict__ att_dst,
        float* __restrict__ a_s, float* __restrict__ a_d, int M,
        const int* __restrict__ ei, int* __restrict__ cursor, int* __restrict__ colv) {
    int b = blockIdx.x;
    if (b < SG_GEMM) {
        gemm_body<128>(b >> 2, b & 3, A, BT, h16, att_src, att_dst, a_s, a_d, M);
        return;
    }
    b -= SG_GEMM;
    int e = b * 256 + threadIdx.x;
    if (e >= TOT_E) return;
    int srcv, dstv;
    if (e < N_EDGES) { srcv = ei[e]; dstv = ei[N_EDGES + e]; }
    else             { srcv = dstv = e - N_EDGES; }
    int pos = atomicAdd(&cursor[dstv], 1);
    colv[pos] = srcv;
}

// ---------------- standalone gemm (layer 1), XCD-swizzled ----------------

template <int K>
__global__ __launch_bounds__(256) void mfma_gemm_att_k(
        const unsigned short* __restrict__ A, const unsigned short* __restrict__ BT,
        unsigned short* __restrict__ h16,
        const float* __restrict__ att_src, const float* __restrict__ att_dst,
        float* __restrict__ a_s, float* __restrict__ a_d, int M) {
    const int bid = blockIdx.x;
    const int xcd = bid & 7;
    const int t   = bid >> 3;
    const int kx  = t & 3;
    const int gy  = xcd + 8 * (t >> 2);
    if (gy >= GY) return;
    gemm_body<K>(gy, kx, A, BT, h16, att_src, att_dst, a_s, a_d, M);
}

// ---------------- aggregation: one wave per destination node (R10 body) ----

__device__ __forceinline__ float lrelu(float x) { return x > 0.f ? x : 0.2f * x; }

template <bool TANH>
__global__ __launch_bounds__(256) void agg_k(const unsigned short* __restrict__ h16,
                      const float* __restrict__ a_s, const float* __restrict__ a_d,
                      const int* __restrict__ start, const int* __restrict__ deg,
                      const int* __restrict__ colv, const float* __restrict__ bias,
                      unsigned short* __restrict__ out16) {
    __shared__ float lexp[4][MAXD][2];
    const int lane = threadIdx.x & 63;
    const int wslot = threadIdx.x >> 6;
    const int node = blockIdx.x * 4 + wslot;
    if (node >= N_NODES) return;
    const int beg = start[node];
    const int degv = deg[node];
    const float ad0 = a_d[node * 2], ad1 = a_d[node * 2 + 1];
    const int* __restrict__ col = colv + beg;

    if (degv <= MAXD) {
        // ---- pass A: gather a_s, exp (max-free), stash to LDS, sum ----
        float s0 = 0.f, s1 = 0.f;
        for (int j = lane; j < degv; j += 64) {
            int s = col[j];
            float2 av = *reinterpret_cast<const float2*>(a_s + s * 2);
            float e0 = __expf(lrelu(av.x + ad0));
            float e1 = __expf(lrelu(av.y + ad1));
            *reinterpret_cast<float2*>(&lexp[wslot][j][0]) = make_float2(e0, e1);
            s0 += e0;
            s1 += e1;
        }
#pragma unroll
        for (int off = 32; off; off >>= 1) {
            s0 += __shfl_xor(s0, off);
            s1 += __shfl_xor(s1, off);
        }
        const float inv0 = 1.f / (s0 + 1e-16f);
        const float inv1 = 1.f / (s1 + 1e-16f);

        // ---- pass B: 4 edges/iter; quarter q owns edge 4i+q; lane covers
        // 16 channels [lq*16, lq*16+16); packed f32x2 accumulate ----
        const int q = lane >> 4;
        const int lq = lane & 15;
        const int cb = lq * 16;
        const int head = lq >> 3;
        const float invh = head ? inv1 : inv0;
        const unsigned short* __restrict__ hp = h16 + cb;
        f32x2 acc2[8] = {};
        const int full = degv >> 2;
        for (int i = 0; i < full; ++i) {
            const int j = 4 * i + q;
            const int s = col[j];
            const float alpha = lexp[wslot][j][head] * invh;
            const f32x2 al = {alpha, alpha};
            const uint4* p = reinterpret_cast<const uint4*>(hp + (size_t)s * HCv);
            const uint4 h0 = p[0];
            const uint4 h1 = p[1];
            fma_row8_pk(h0, al, acc2);
            fma_row8_pk(h1, al, acc2 + 4);
        }
        {   // tail (degv & 3 edges)
            const int j = full * 4 + q;
            if (j < degv) {
                const int s = col[j];
                const float alpha = lexp[wslot][j][head] * invh;
                const f32x2 al = {alpha, alpha};
                const uint4* p = reinterpret_cast<const uint4*>(hp + (size_t)s * HCv);
                const uint4 h0 = p[0];
                const uint4 h1 = p[1];
                fma_row8_pk(h0, al, acc2);
                fma_row8_pk(h1, al, acc2 + 4);
            }
        }
        float acc[16];
#pragma unroll
        for (int c = 0; c < 8; ++c) {
            acc[2 * c]     = acc2[c].x;
            acc[2 * c + 1] = acc2[c].y;
        }
#pragma unroll
        for (int c = 0; c < 16; ++c) {
            acc[c] += __shfl_xor(acc[c], 16);
            acc[c] += __shfl_xor(acc[c], 32);
        }
        if (lane < 16) {
#pragma unroll
            for (int c = 0; c < 16; ++c) acc[c] += bias[cb + c];
            if (TANH) {
#pragma unroll
                for (int c = 0; c < 16; ++c) acc[c] = tanhf(acc[c]);
            }
            uint4 v0, v1;
            v0.x = f2bf_pack(acc[0], acc[1]);
            v0.y = f2bf_pack(acc[2], acc[3]);
            v0.z = f2bf_pack(acc[4], acc[5]);
            v0.w = f2bf_pack(acc[6], acc[7]);
            v1.x = f2bf_pack(acc[8], acc[9]);
            v1.y = f2bf_pack(acc[10], acc[11]);
            v1.z = f2bf_pack(acc[12], acc[13]);
            v1.w = f2bf_pack(acc[14], acc[15]);
            uint4* o = reinterpret_cast<uint4*>(out16 + (size_t)node * HCv + cb);
            o[0] = v0;
            o[1] = v1;
        }
    } else {
        // ---- fallback: 3-pass recompute path (deg > MAXD) ----
        const int end = beg + degv;
        float m0 = -INFINITY, m1 = -INFINITY;
        for (int e = beg + lane; e < end; e += 64) {
            int s = colv[e];
            m0 = fmaxf(m0, lrelu(a_s[s * 2] + ad0));
            m1 = fmaxf(m1, lrelu(a_s[s * 2 + 1] + ad1));
        }
#pragma unroll
        for (int off = 32; off; off >>= 1) {
            m0 = fmaxf(m0, __shfl_xor(m0, off));
            m1 = fmaxf(m1, __shfl_xor(m1, off));
        }
        float s0 = 0.f, s1 = 0.f;
        for (int e = beg + lane; e < end; e += 64) {
            int s = colv[e];
            s0 += __expf(lrelu(a_s[s * 2] + ad0) - m0);
            s1 += __expf(lrelu(a_s[s * 2 + 1] + ad1) - m1);
        }
#pragma unroll
        for (int off = 32; off; off >>= 1) {
            s0 += __shfl_xor(s0, off);
            s1 += __shfl_xor(s1, off);
        }
        float inv0 = 1.f / (s0 + 1e-16f);
        float inv1 = 1.f / (s1 + 1e-16f);
        const int head = lane >> 5;
        const float mh  = head ? m1 : m0;
        const float ih  = head ? inv1 : inv0;
        const float adh = head ? ad1 : ad0;
        const int cbase = lane * 4;
        float acc0 = 0.f, acc1 = 0.f, acc2 = 0.f, acc3 = 0.f;
        for (int e = beg; e < end; ++e) {
            int s = colv[e];
            float l = lrelu(a_s[s * 2 + head] + adh);
            float alpha = __expf(l - mh) * ih;
            uint2 hv = *reinterpret_cast<const uint2*>(h16 + (size_t)s * HCv + cbase);
            acc0 = fmaf(bf2f_lo(hv.x), alpha, acc0);
            acc1 = fmaf(bf2f_hi(hv.x), alpha, acc1);
            acc2 = fmaf(bf2f_lo(hv.y), alpha, acc2);
            acc3 = fmaf(bf2f_hi(hv.y), alpha, acc3);
        }
        float o0 = acc0 + bias[cbase + 0];
        float o1 = acc1 + bias[cbase + 1];
        float o2 = acc2 + bias[cbase + 2];
        float o3 = acc3 + bias[cbase + 3];
        if (TANH) {
            o0 = tanhf(o0); o1 = tanhf(o1); o2 = tanhf(o2); o3 = tanhf(o3);
        }
        ushort4 v;
        v.x = f2bf(o0); v.y = f2bf(o1); v.z = f2bf(o2); v.w = f2bf(o3);
        *reinterpret_cast<ushort4*>(out16 + (size_t)node * HCv + cbase) = v;
    }
}

// ---------------- final linear (256 -> 2) + softmax, bf16 input ----------------

__global__ void final_k(const unsigned short* __restrict__ h, const float* __restrict__ Wl,
                        const float* __restrict__ bl, float* __restrict__ out) {
    int lane = threadIdx.x & 63;
    int node = blockIdx.x * 4 + (threadIdx.x >> 6);
    if (node >= N_NODES) return;
    const int c = lane * 4;
    uint2 hv = *reinterpret_cast<const uint2*>(h + (size_t)node * HCv + c);
    float v0 = bf2f_lo(hv.x), v1 = bf2f_hi(hv.x);
    float v2 = bf2f_lo(hv.y), v3 = bf2f_hi(hv.y);
    float o0 = v0 * Wl[(c + 0) * 2 + 0] + v1 * Wl[(c + 1) * 2 + 0]
             + v2 * Wl[(c + 2) * 2 + 0] + v3 * Wl[(c + 3) * 2 + 0];
    float o1 = v0 * Wl[(c + 0) * 2 + 1] + v1 * Wl[(c + 1) * 2 + 1]
             + v2 * Wl[(c + 2) * 2 + 1] + v3 * Wl[(c + 3) * 2 + 1];
#pragma unroll
    for (int off = 32; off; off >>= 1) {
        o0 += __shfl_down(o0, off);
        o1 += __shfl_down(o1, off);
    }
    if (lane == 0) {
        o0 += bl[0];
        o1 += bl[1];
        float mx = fmaxf(o0, o1);
        float e0 = __expf(o0 - mx), e1 = __expf(o1 - mx);
        float inv = 1.f / (e0 + e1);
        out[node * 2 + 0] = e0 * inv;
        out[node * 2 + 1] = e1 * inv;
    }
}

// ---------------- launch ----------------

extern "C" void kernel_launch(void* const* d_in, const int* in_sizes, int n_in,
                              void* d_out, int out_size, void* d_ws, size_t ws_size,
                              hipStream_t stream) {
    const float* x        = (const float*)d_in[0];
    const int*   ei       = (const int*)d_in[1];
    const float* W0       = (const float*)d_in[2];
    const float* att_src0 = (const float*)d_in[3];
    const float* att_dst0 = (const float*)d_in[4];
    const float* b0       = (const float*)d_in[5];
    const float* W1       = (const float*)d_in[6];
    const float* att_src1 = (const float*)d_in[7];
    const float* att_dst1 = (const float*)d_in[8];
    const float* b1       = (const float*)d_in[9];
    const float* Wl       = (const float*)d_in[10];
    const float* bl       = (const float*)d_in[11];
    float* out = (float*)d_out;

    // workspace layout
    unsigned short* xb     = (unsigned short*)d_ws;               // N*128 bf16
    unsigned short* h16    = xb + (size_t)N_NODES * 128;          // N*256 bf16 (gemm out)
    unsigned short* hact16 = h16 + (size_t)N_NODES * HCv;         // N*256 bf16 (agg out)
    unsigned short* WT0    = hact16 + (size_t)N_NODES * HCv;      // 256*128 bf16
    unsigned short* WT1    = WT0 + 256 * 128;                     // 256*256 bf16
    float* a_sd = (float*)(WT1 + 256 * 256);                      // N*8 (both layers)
    float* as0  = a_sd;                                           // N*2
    float* ad0  = as0 + N_NODES * 2;                              // N*2
    float* as1  = ad0 + N_NODES * 2;                              // N*2
    float* ad1  = as1 + N_NODES * 2;                              // N*2
    int* deg    = (int*)(ad1 + N_NODES * 2);                      // N
    int* total  = deg + N_NODES;                                  // 1
    int* start  = total + 1;                                      // N
    int* cursor = start + N_NODES;                                // N
    int* colv   = cursor + N_NODES;                               // E + N

    // ---- fused prep (cvt x, WT0/WT1, degree count, zero both a_s/a_d sets) ----
    hipMemsetAsync(deg, 0, (N_NODES + 1) * sizeof(int), stream);  // deg + total
    prep_k<<<PREP_BLKS, 256, 0, stream>>>(x, xb, W0, WT0, W1, WT1, ei, deg, a_sd);

    // ---- CSR offsets ----
    offsets_k<<<(N_NODES + 255) / 256, 256, 0, stream>>>(deg, start, cursor, total);

    int nn4 = (N_NODES + 3) / 4;

    // ---- layer-0 GEMM || CSR scatter (independent; merged launch) ----
    sg_k<<<SG_BLKS, 256, 0, stream>>>(xb, WT0, h16, att_src0, att_dst0,
                                      as0, ad0, N_NODES, ei, cursor, colv);
    agg_k<true><<<nn4, 256, 0, stream>>>(h16, as0, ad0, start, deg, colv, b0, hact16);

    // ---- layer 1 ----
    mfma_gemm_att_k<256><<<GEMM_BLKS, 256, 0, stream>>>(hact16, WT1, h16, att_src1, att_dst1,
                                                        as1, ad1, N_NODES);
    agg_k<false><<<nn4, 256, 0, stream>>>(h16, as1, ad1, start, deg, colv, b1, hact16);

    // ---- final linear + softmax (bf16 input) ----
    final_k<<<nn4, 256, 0, stream>>>(hact16, Wl, bl, out);
}

// Round 12
// 335.124 us; speedup vs baseline: 1.0114x; 1.0114x over previous
//
#include <hip/hip_runtime.h>
#include <math.h>

// Problem constants (from reference)
constexpr int N_NODES = 50000;
constexpr int N_EDGES = 800000;
constexpr int TOT_E   = N_EDGES + N_NODES;   // + self loops
constexpr int HCv     = 256;                 // H*C
constexpr int MAXD    = 256;                 // LDS logit-cache capacity per wave

// GEMM grid geometry (XCD-swizzled 1-D launch; bid%8 == XCD round-robin)
constexpr int GY        = (N_NODES + 127) / 128;  // 391 row-tiles
constexpr int GPX       = (GY + 7) / 8;           // 49 row-tiles per XCD
constexpr int GEMM_BLKS = 8 * GPX * 4;            // 1568 (tail guarded)

// padded atomic counters: one int per 128B line (stride 32 ints)
constexpr int PADSH = 5;                          // <<5

// prep_k section sizes
constexpr int PREP_CVT   = (N_NODES * 128 / 4 + 255) / 256;   // 6250
constexpr int PREP_WT0   = 128;
constexpr int PREP_WT1   = 256;
constexpr int PREP_DEG   = (TOT_E + 255) / 256;               // 3321
constexpr int PREP_ZERO  = (N_NODES * 8 / 4 + 255) / 256;     // 196 (a_sd only)
constexpr int PREP_BLKS  = PREP_CVT + PREP_WT0 + PREP_WT1 + PREP_DEG + PREP_ZERO;

typedef __attribute__((ext_vector_type(8))) short bf16x8;
typedef __attribute__((ext_vector_type(4))) float f32x4;
typedef __attribute__((ext_vector_type(2))) float f32x2;

// ---- bf16 helpers (manual RNE, deterministic) ----
__device__ __forceinline__ unsigned short f2bf(float f) {
    unsigned int u = __float_as_uint(f);
    unsigned int r = (u + 0x7fffu + ((u >> 16) & 1u)) >> 16;
    return (unsigned short)r;
}
__device__ __forceinline__ unsigned int f2bf_pack(float lo, float hi) {
    return (unsigned int)f2bf(lo) | ((unsigned int)f2bf(hi) << 16);
}
__device__ __forceinline__ float bf2f_lo(unsigned int packed) {
    return __uint_as_float(packed << 16);
}
__device__ __forceinline__ float bf2f_hi(unsigned int packed) {
    return __uint_as_float(packed & 0xffff0000u);
}

// 8 bf16 channels += alpha * row-fragment, packed f32x2
__device__ __forceinline__ void fma_row8_pk(const uint4 h, f32x2 al, f32x2* a2) {
    f32x2 p;
    p.x = bf2f_lo(h.x); p.y = bf2f_hi(h.x);
    a2[0] = __builtin_elementwise_fma(p, al, a2[0]);
    p.x = bf2f_lo(h.y); p.y = bf2f_hi(h.y);
    a2[1] = __builtin_elementwise_fma(p, al, a2[1]);
    p.x = bf2f_lo(h.z); p.y = bf2f_hi(h.z);
    a2[2] = __builtin_elementwise_fma(p, al, a2[2]);
    p.x = bf2f_lo(h.w); p.y = bf2f_hi(h.w);
    a2[3] = __builtin_elementwise_fma(p, al, a2[3]);
}

// ---------------- zero padded degree counters (runs before prep) ----------------

__global__ void zero_degp_k(uint4* __restrict__ degp4) {
    int i = blockIdx.x * blockDim.x + threadIdx.x;
    if (i < N_NODES * 32 / 4) degp4[i] = make_uint4(0, 0, 0, 0);
}

// ---------------- fused prep: cvt x, transpose W0/W1, count degrees (padded),
// zero both layers' a_s/a_d ----

__global__ __launch_bounds__(256) void prep_k(const float* __restrict__ x,
                                              unsigned short* __restrict__ xb,
                                              const float* __restrict__ W0,
                                              unsigned short* __restrict__ WT0,
                                              const float* __restrict__ W1,
                                              unsigned short* __restrict__ WT1,
                                              const int* __restrict__ ei,
                                              int* __restrict__ degp,
                                              float* __restrict__ a_sd) {
    int b = blockIdx.x;
    if (b < PREP_CVT) {                       // x -> bf16 (float4 quads)
        int i = b * 256 + threadIdx.x;
        if (i < N_NODES * 128 / 4) {
            float4 v = *reinterpret_cast<const float4*>(x + (size_t)i * 4);
            ushort4 o;
            o.x = f2bf(v.x); o.y = f2bf(v.y); o.z = f2bf(v.z); o.w = f2bf(v.w);
            *reinterpret_cast<ushort4*>(xb + (size_t)i * 4) = o;
        }
        return;
    }
    b -= PREP_CVT;
    if (b < PREP_WT0) {                       // WT0[n][k] = bf16(W0[k][n]), K=128
        int idx = b * 256 + threadIdx.x;
        int k = idx >> 8, n = idx & 255;
        WT0[(size_t)n * 128 + k] = f2bf(W0[idx]);
        return;
    }
    b -= PREP_WT0;
    if (b < PREP_WT1) {                       // WT1[n][k] = bf16(W1[k][n]), K=256
        int idx = b * 256 + threadIdx.x;
        int k = idx >> 8, n = idx & 255;
        WT1[(size_t)n * 256 + k] = f2bf(W1[idx]);
        return;
    }
    b -= PREP_WT1;
    if (b < PREP_DEG) {                       // degree count (padded counters)
        int e = b * 256 + threadIdx.x;
        if (e < TOT_E) {
            int dst = (e < N_EDGES) ? ei[N_EDGES + e] : (e - N_EDGES);
            atomicAdd(&degp[dst << PADSH], 1);
        }
        return;
    }
    b -= PREP_DEG;
    {                                         // zero a_s/a_d for BOTH layers
        int i = b * 256 + threadIdx.x;
        if (i < N_NODES * 2)
            *reinterpret_cast<float4*>(a_sd + (size_t)i * 4) = make_float4(0, 0, 0, 0);
    }
}

// ---------------- CSR build ----------------

__global__ void offsets_k(const int* __restrict__ degp, int* __restrict__ start,
                          int* __restrict__ deg, int* __restrict__ cursorp,
                          int* __restrict__ total) {
    int lane = threadIdx.x & 63;
    int node = blockIdx.x * blockDim.x + threadIdx.x;
    int d = (node < N_NODES) ? degp[node << PADSH] : 0;
    int pre = d;
#pragma unroll
    for (int off = 1; off < 64; off <<= 1) {
        int v = __shfl_up(pre, off);
        if (lane >= off) pre += v;
    }
    int wtot = __shfl(pre, 63);
    int base = 0;
    if (lane == 63) base = atomicAdd(total, wtot);
    base = __shfl(base, 63);
    int my = base + pre - d;
    if (node < N_NODES) {
        start[node] = my;
        deg[node] = d;
        cursorp[node << PADSH] = my;
    }
}

__global__ void scatter_k(const int* __restrict__ ei, int* __restrict__ cursorp,
                          int* __restrict__ colv) {
    int e = blockIdx.x * blockDim.x + threadIdx.x;
    if (e >= TOT_E) return;
    int srcv, dstv;
    if (e < N_EDGES) { srcv = ei[e]; dstv = ei[N_EDGES + e]; }
    else             { srcv = dstv = e - N_EDGES; }
    int pos = atomicAdd(&cursorp[dstv << PADSH], 1);
    colv[pos] = srcv;
}

// ---------------- MFMA bf16 GEMM + fused attention epilogue ----------------

template <int K>
__global__ __launch_bounds__(256) void mfma_gemm_att_k(
        const unsigned short* __restrict__ A,   // [M][K] bf16
        const unsigned short* __restrict__ BT,  // [256][K] bf16 (W transposed)
        unsigned short* __restrict__ h16,       // [M][256] bf16 out
        const float* __restrict__ att_src, const float* __restrict__ att_dst,
        float* __restrict__ a_s, float* __restrict__ a_d, int M) {
    const int bid = blockIdx.x;
    const int xcd = bid & 7;
    const int t   = bid >> 3;
    const int kx  = t & 3;
    const int gy  = xcd + 8 * (t >> 2);
    if (gy >= GY) return;

    const int lane = threadIdx.x & 63;
    const int wv = threadIdx.x >> 6;
    const int lm = lane & 15;
    const int g8 = (lane >> 4) * 8;
    const int row0 = gy * 128 + wv * 32;
    const int n0 = kx * 64;

    int ra0 = row0 + lm;       if (ra0 >= M) ra0 = M - 1;
    int ra1 = row0 + 16 + lm;  if (ra1 >= M) ra1 = M - 1;
    const unsigned short* pa0 = A + (size_t)ra0 * K + g8;
    const unsigned short* pa1 = A + (size_t)ra1 * K + g8;
    const unsigned short* pb  = BT + (size_t)(n0 + lm) * K + g8;

    f32x4 acc[2][4] = {};
#pragma unroll
    for (int kt = 0; kt < K; kt += 32) {
        bf16x8 a0 = *reinterpret_cast<const bf16x8*>(pa0 + kt);
        bf16x8 a1 = *reinterpret_cast<const bf16x8*>(pa1 + kt);
        bf16x8 b0 = *reinterpret_cast<const bf16x8*>(pb + kt);
        bf16x8 b1 = *reinterpret_cast<const bf16x8*>(pb + 16 * K + kt);
        bf16x8 b2 = *reinterpret_cast<const bf16x8*>(pb + 32 * K + kt);
        bf16x8 b3 = *reinterpret_cast<const bf16x8*>(pb + 48 * K + kt);
        acc[0][0] = __builtin_amdgcn_mfma_f32_16x16x32_bf16(a0, b0, acc[0][0], 0, 0, 0);
        acc[0][1] = __builtin_amdgcn_mfma_f32_16x16x32_bf16(a0, b1, acc[0][1], 0, 0, 0);
        acc[0][2] = __builtin_amdgcn_mfma_f32_16x16x32_bf16(a0, b2, acc[0][2], 0, 0, 0);
        acc[0][3] = __builtin_amdgcn_mfma_f32_16x16x32_bf16(a0, b3, acc[0][3], 0, 0, 0);
        acc[1][0] = __builtin_amdgcn_mfma_f32_16x16x32_bf16(a1, b0, acc[1][0], 0, 0, 0);
        acc[1][1] = __builtin_amdgcn_mfma_f32_16x16x32_bf16(a1, b1, acc[1][1], 0, 0, 0);
        acc[1][2] = __builtin_amdgcn_mfma_f32_16x16x32_bf16(a1, b2, acc[1][2], 0, 0, 0);
        acc[1][3] = __builtin_amdgcn_mfma_f32_16x16x32_bf16(a1, b3, acc[1][3], 0, 0, 0);
    }

    float as_c[4], ad_c[4];
#pragma unroll
    for (int j = 0; j < 4; ++j) {
        int c = n0 + j * 16 + lm;
        as_c[j] = att_src[c];
        ad_c[j] = att_dst[c];
    }
    const int head = n0 >> 7;

#pragma unroll
    for (int i = 0; i < 2; ++i) {
        float ps[4] = {}, pd[4] = {};
#pragma unroll
        for (int j = 0; j < 4; ++j)
#pragma unroll
            for (int r = 0; r < 4; ++r) {
                ps[r] += acc[i][j][r] * as_c[j];
                pd[r] += acc[i][j][r] * ad_c[j];
            }
#pragma unroll
        for (int off = 1; off < 16; off <<= 1)
#pragma unroll
            for (int r = 0; r < 4; ++r) {
                ps[r] += __shfl_xor(ps[r], off);
                pd[r] += __shfl_xor(pd[r], off);
            }
        if (lm == 0) {
            int rb = row0 + i * 16 + (lane >> 4) * 4;
#pragma unroll
            for (int r = 0; r < 4; ++r) {
                if (rb + r < M) {
                    atomicAdd(&a_s[(rb + r) * 2 + head], ps[r]);
                    atomicAdd(&a_d[(rb + r) * 2 + head], pd[r]);
                }
            }
        }
#pragma unroll
        for (int j = 0; j < 4; ++j)
#pragma unroll
            for (int r = 0; r < 4; ++r) {
                int row = row0 + i * 16 + (lane >> 4) * 4 + r;
                if (row < M)
                    h16[(size_t)row * HCv + n0 + j * 16 + lm] = f2bf(acc[i][j][r]);
            }
    }
}

// ---------------- aggregation: one wave per destination node (R10 body) ----

__device__ __forceinline__ float lrelu(float x) { return x > 0.f ? x : 0.2f * x; }

template <bool TANH>
__global__ __launch_bounds__(256) void agg_k(const unsigned short* __restrict__ h16,
                      const float* __restrict__ a_s, const float* __restrict__ a_d,
                      const int* __restrict__ start, const int* __restrict__ deg,
                      const int* __restrict__ colv, const float* __restrict__ bias,
                      unsigned short* __restrict__ out16) {
    __shared__ float lexp[4][MAXD][2];
    const int lane = threadIdx.x & 63;
    const int wslot = threadIdx.x >> 6;
    const int node = blockIdx.x * 4 + wslot;
    if (node >= N_NODES) return;
    const int beg = start[node];
    const int degv = deg[node];
    const float ad0 = a_d[node * 2], ad1 = a_d[node * 2 + 1];
    const int* __restrict__ col = colv + beg;

    if (degv <= MAXD) {
        // ---- pass A: gather a_s, exp (max-free), stash to LDS, sum ----
        float s0 = 0.f, s1 = 0.f;
        for (int j = lane; j < degv; j += 64) {
            int s = col[j];
            float2 av = *reinterpret_cast<const float2*>(a_s + s * 2);
            float e0 = __expf(lrelu(av.x + ad0));
            float e1 = __expf(lrelu(av.y + ad1));
            *reinterpret_cast<float2*>(&lexp[wslot][j][0]) = make_float2(e0, e1);
            s0 += e0;
            s1 += e1;
        }
#pragma unroll
        for (int off = 32; off; off >>= 1) {
            s0 += __shfl_xor(s0, off);
            s1 += __shfl_xor(s1, off);
        }
        const float inv0 = 1.f / (s0 + 1e-16f);
        const float inv1 = 1.f / (s1 + 1e-16f);

        // ---- pass B: 4 edges/iter; quarter q owns edge 4i+q; lane covers
        // 16 channels [lq*16, lq*16+16); packed f32x2 accumulate ----
        const int q = lane >> 4;
        const int lq = lane & 15;
        const int cb = lq * 16;
        const int head = lq >> 3;
        const float invh = head ? inv1 : inv0;
        const unsigned short* __restrict__ hp = h16 + cb;
        f32x2 acc2[8] = {};
        const int full = degv >> 2;
        for (int i = 0; i < full; ++i) {
            const int j = 4 * i + q;
            const int s = col[j];
            const float alpha = lexp[wslot][j][head] * invh;
            const f32x2 al = {alpha, alpha};
            const uint4* p = reinterpret_cast<const uint4*>(hp + (size_t)s * HCv);
            const uint4 h0 = p[0];
            const uint4 h1 = p[1];
            fma_row8_pk(h0, al, acc2);
            fma_row8_pk(h1, al, acc2 + 4);
        }
        {   // tail (degv & 3 edges)
            const int j = full * 4 + q;
            if (j < degv) {
                const int s = col[j];
                const float alpha = lexp[wslot][j][head] * invh;
                const f32x2 al = {alpha, alpha};
                const uint4* p = reinterpret_cast<const uint4*>(hp + (size_t)s * HCv);
                const uint4 h0 = p[0];
                const uint4 h1 = p[1];
                fma_row8_pk(h0, al, acc2);
                fma_row8_pk(h1, al, acc2 + 4);
            }
        }
        float acc[16];
#pragma unroll
        for (int c = 0; c < 8; ++c) {
            acc[2 * c]     = acc2[c].x;
            acc[2 * c + 1] = acc2[c].y;
        }
#pragma unroll
        for (int c = 0; c < 16; ++c) {
            acc[c] += __shfl_xor(acc[c], 16);
            acc[c] += __shfl_xor(acc[c], 32);
        }
        if (lane < 16) {
#pragma unroll
            for (int c = 0; c < 16; ++c) acc[c] += bias[cb + c];
            if (TANH) {
#pragma unroll
                for (int c = 0; c < 16; ++c) acc[c] = tanhf(acc[c]);
            }
            uint4 v0, v1;
            v0.x = f2bf_pack(acc[0], acc[1]);
            v0.y = f2bf_pack(acc[2], acc[3]);
            v0.z = f2bf_pack(acc[4], acc[5]);
            v0.w = f2bf_pack(acc[6], acc[7]);
            v1.x = f2bf_pack(acc[8], acc[9]);
            v1.y = f2bf_pack(acc[10], acc[11]);
            v1.z = f2bf_pack(acc[12], acc[13]);
            v1.w = f2bf_pack(acc[14], acc[15]);
            uint4* o = reinterpret_cast<uint4*>(out16 + (size_t)node * HCv + cb);
            o[0] = v0;
            o[1] = v1;
        }
    } else {
        // ---- fallback: 3-pass recompute path (deg > MAXD) ----
        const int end = beg + degv;
        float m0 = -INFINITY, m1 = -INFINITY;
        for (int e = beg + lane; e < end; e += 64) {
            int s = colv[e];
            m0 = fmaxf(m0, lrelu(a_s[s * 2] + ad0));
            m1 = fmaxf(m1, lrelu(a_s[s * 2 + 1] + ad1));
        }
#pragma unroll
        for (int off = 32; off; off >>= 1) {
            m0 = fmaxf(m0, __shfl_xor(m0, off));
            m1 = fmaxf(m1, __shfl_xor(m1, off));
        }
        float s0 = 0.f, s1 = 0.f;
        for (int e = beg + lane; e < end; e += 64) {
            int s = colv[e];
            s0 += __expf(lrelu(a_s[s * 2] + ad0) - m0);
            s1 += __expf(lrelu(a_s[s * 2 + 1] + ad1) - m1);
        }
#pragma unroll
        for (int off = 32; off; off >>= 1) {
            s0 += __shfl_xor(s0, off);
            s1 += __shfl_xor(s1, off);
        }
        float inv0 = 1.f / (s0 + 1e-16f);
        float inv1 = 1.f / (s1 + 1e-16f);
        const int head = lane >> 5;
        const float mh  = head ? m1 : m0;
        const float ih  = head ? inv1 : inv0;
        const float adh = head ? ad1 : ad0;
        const int cbase = lane * 4;
        float acc0 = 0.f, acc1 = 0.f, acc2 = 0.f, acc3 = 0.f;
        for (int e = beg; e < end; ++e) {
            int s = colv[e];
            float l = lrelu(a_s[s * 2 + head] + adh);
            float alpha = __expf(l - mh) * ih;
            uint2 hv = *reinterpret_cast<const uint2*>(h16 + (size_t)s * HCv + cbase);
            acc0 = fmaf(bf2f_lo(hv.x), alpha, acc0);
            acc1 = fmaf(bf2f_hi(hv.x), alpha, acc1);
            acc2 = fmaf(bf2f_lo(hv.y), alpha, acc2);
            acc3 = fmaf(bf2f_hi(hv.y), alpha, acc3);
        }
        float o0 = acc0 + bias[cbase + 0];
        float o1 = acc1 + bias[cbase + 1];
        float o2 = acc2 + bias[cbase + 2];
        float o3 = acc3 + bias[cbase + 3];
        if (TANH) {
            o0 = tanhf(o0); o1 = tanhf(o1); o2 = tanhf(o2); o3 = tanhf(o3);
        }
        ushort4 v;
        v.x = f2bf(o0); v.y = f2bf(o1); v.z = f2bf(o2); v.w = f2bf(o3);
        *reinterpret_cast<ushort4*>(out16 + (size_t)node * HCv + cbase) = v;
    }
}

// ---------------- final linear (256 -> 2) + softmax, bf16 input ----------------

__global__ void final_k(const unsigned short* __restrict__ h, const float* __restrict__ Wl,
                        const float* __restrict__ bl, float* __restrict__ out) {
    int lane = threadIdx.x & 63;
    int node = blockIdx.x * 4 + (threadIdx.x >> 6);
    if (node >= N_NODES) return;
    const int c = lane * 4;
    uint2 hv = *reinterpret_cast<const uint2*>(h + (size_t)node * HCv + c);
    float v0 = bf2f_lo(hv.x), v1 = bf2f_hi(hv.x);
    float v2 = bf2f_lo(hv.y), v3 = bf2f_hi(hv.y);
    float o0 = v0 * Wl[(c + 0) * 2 + 0] + v1 * Wl[(c + 1) * 2 + 0]
             + v2 * Wl[(c + 2) * 2 + 0] + v3 * Wl[(c + 3) * 2 + 0];
    float o1 = v0 * Wl[(c + 0) * 2 + 1] + v1 * Wl[(c + 1) * 2 + 1]
             + v2 * Wl[(c + 2) * 2 + 1] + v3 * Wl[(c + 3) * 2 + 1];
#pragma unroll
    for (int off = 32; off; off >>= 1) {
        o0 += __shfl_down(o0, off);
        o1 += __shfl_down(o1, off);
    }
    if (lane == 0) {
        o0 += bl[0];
        o1 += bl[1];
        float mx = fmaxf(o0, o1);
        float e0 = __expf(o0 - mx), e1 = __expf(o1 - mx);
        float inv = 1.f / (e0 + e1);
        out[node * 2 + 0] = e0 * inv;
        out[node * 2 + 1] = e1 * inv;
    }
}

// ---------------- launch ----------------

extern "C" void kernel_launch(void* const* d_in, const int* in_sizes, int n_in,
                              void* d_out, int out_size, void* d_ws, size_t ws_size,
                              hipStream_t stream) {
    const float* x        = (const float*)d_in[0];
    const int*   ei       = (const int*)d_in[1];
    const float* W0       = (const float*)d_in[2];
    const float* att_src0 = (const float*)d_in[3];
    const float* att_dst0 = (const float*)d_in[4];
    const float* b0       = (const float*)d_in[5];
    const float* W1       = (const float*)d_in[6];
    const float* att_src1 = (const float*)d_in[7];
    const float* att_dst1 = (const float*)d_in[8];
    const float* b1       = (const float*)d_in[9];
    const float* Wl       = (const float*)d_in[10];
    const float* bl       = (const float*)d_in[11];
    float* out = (float*)d_out;

    // workspace layout
    unsigned short* xb     = (unsigned short*)d_ws;               // N*128 bf16
    unsigned short* h16    = xb + (size_t)N_NODES * 128;          // N*256 bf16
    unsigned short* hact16 = h16 + (size_t)N_NODES * HCv;         // N*256 bf16
    unsigned short* WT0    = hact16 + (size_t)N_NODES * HCv;      // 256*128 bf16
    unsigned short* WT1    = WT0 + 256 * 128;                     // 256*256 bf16
    int*   degp  = (int*)(WT1 + 256 * 256);                       // N*32 (padded)
    float* a_sd  = (float*)(degp + (size_t)N_NODES * 32);         // N*8 (both layers)
    float* as0   = a_sd;
    float* ad0   = as0 + N_NODES * 2;
    float* as1   = ad0 + N_NODES * 2;
    float* ad1   = as1 + N_NODES * 2;
    int* cursorp = (int*)(ad1 + N_NODES * 2);                     // N*32 (padded)
    int* deg     = cursorp + (size_t)N_NODES * 32;                // N (compact)
    int* start   = deg + N_NODES;                                 // N
    int* total   = start + N_NODES;                               // 1
    int* colv    = total + 1;                                     // E + N

    hipMemsetAsync(total, 0, sizeof(int), stream);

    // ---- zero padded deg counters, then fused prep (cvt/WT/deg-count/zero a_sd) ----
    zero_degp_k<<<(N_NODES * 32 / 4 + 255) / 256, 256, 0, stream>>>((uint4*)degp);
    prep_k<<<PREP_BLKS, 256, 0, stream>>>(x, xb, W0, WT0, W1, WT1, ei, degp, a_sd);

    // ---- CSR offsets + scatter (padded cursors) ----
    offsets_k<<<(N_NODES + 255) / 256, 256, 0, stream>>>(degp, start, deg, cursorp, total);
    scatter_k<<<(TOT_E + 255) / 256, 256, 0, stream>>>(ei, cursorp, colv);

    int nn4 = (N_NODES + 3) / 4;

    // ---- layer 0 ----
    mfma_gemm_att_k<128><<<GEMM_BLKS, 256, 0, stream>>>(xb, WT0, h16, att_src0, att_dst0,
                                                        as0, ad0, N_NODES);
    agg_k<true><<<nn4, 256, 0, stream>>>(h16, as0, ad0, start, deg, colv, b0, hact16);

    // ---- layer 1 ----
    mfma_gemm_att_k<256><<<GEMM_BLKS, 256, 0, stream>>>(hact16, WT1, h16, att_src1, att_dst1,
                                                        as1, ad1, N_NODES);
    agg_k<false><<<nn4, 256, 0, stream>>>(h16, as1, ad1, start, deg, colv, b1, hact16);

    // ---- final linear + softmax (bf16 input) ----
    final_k<<<nn4, 256, 0, stream>>>(hact16, Wl, bl, out);
}

// Round 13
// 315.856 us; speedup vs baseline: 1.0731x; 1.0610x over previous
//
#include <hip/hip_runtime.h>
#include <math.h>

// Problem constants (from reference)
constexpr int N_NODES = 50000;
constexpr int N_EDGES = 800000;
constexpr int TOT_E   = N_EDGES + N_NODES;   // + self loops
constexpr int HCv     = 256;                 // H*C
constexpr int MAXD    = 256;                 // LDS logit-cache capacity per wave

// GEMM grid geometry (XCD-swizzled 1-D launch; bid%8 == XCD round-robin)
constexpr int GY        = (N_NODES + 127) / 128;  // 391 row-tiles
constexpr int GPX       = (GY + 7) / 8;           // 49 row-tiles per XCD
constexpr int GEMM_BLKS = 8 * GPX * 4;            // 1568 (tail guarded)

// padded atomic counters: one int per 128B line (stride 32 ints)
constexpr int PADSH = 5;                          // <<5

// prep_k section sizes
constexpr int PREP_CVT   = (N_NODES * 128 / 4 + 255) / 256;   // 6250
constexpr int PREP_WT0   = 128;
constexpr int PREP_WT1   = 256;
constexpr int PREP_DEG   = (TOT_E + 255) / 256;               // 3321
constexpr int PREP_ZERO  = (N_NODES * 12 / 4 + 255) / 256;    // 587 (as0,ad0,as1,ad1,g)
constexpr int PREP_C     = 1;                                 // c = Wl^T b1 + bl
constexpr int PREP_BLKS  = PREP_CVT + PREP_WT0 + PREP_WT1 + PREP_DEG + PREP_ZERO + PREP_C;

typedef __attribute__((ext_vector_type(8))) short bf16x8;
typedef __attribute__((ext_vector_type(4))) float f32x4;
typedef __attribute__((ext_vector_type(2))) float f32x2;

// ---- bf16 helpers (manual RNE, deterministic) ----
__device__ __forceinline__ unsigned short f2bf(float f) {
    unsigned int u = __float_as_uint(f);
    unsigned int r = (u + 0x7fffu + ((u >> 16) & 1u)) >> 16;
    return (unsigned short)r;
}
__device__ __forceinline__ unsigned int f2bf_pack(float lo, float hi) {
    return (unsigned int)f2bf(lo) | ((unsigned int)f2bf(hi) << 16);
}
__device__ __forceinline__ float bf2f_lo(unsigned int packed) {
    return __uint_as_float(packed << 16);
}
__device__ __forceinline__ float bf2f_hi(unsigned int packed) {
    return __uint_as_float(packed & 0xffff0000u);
}

// 8 bf16 channels += alpha * row-fragment, packed f32x2
__device__ __forceinline__ void fma_row8_pk(const uint4 h, f32x2 al, f32x2* a2) {
    f32x2 p;
    p.x = bf2f_lo(h.x); p.y = bf2f_hi(h.x);
    a2[0] = __builtin_elementwise_fma(p, al, a2[0]);
    p.x = bf2f_lo(h.y); p.y = bf2f_hi(h.y);
    a2[1] = __builtin_elementwise_fma(p, al, a2[1]);
    p.x = bf2f_lo(h.z); p.y = bf2f_hi(h.z);
    a2[2] = __builtin_elementwise_fma(p, al, a2[2]);
    p.x = bf2f_lo(h.w); p.y = bf2f_hi(h.w);
    a2[3] = __builtin_elementwise_fma(p, al, a2[3]);
}

// ---------------- zero padded degree counters + total + c (runs before prep) ----

__global__ void zero_degp_k(uint4* __restrict__ degp4, int* __restrict__ total,
                            float* __restrict__ c2) {
    int i = blockIdx.x * blockDim.x + threadIdx.x;
    if (i < N_NODES * 32 / 4) degp4[i] = make_uint4(0, 0, 0, 0);
    if (blockIdx.x == 0 && threadIdx.x == 0) {
        *total = 0;
        c2[0] = 0.f;
        c2[1] = 0.f;
    }
}

// ---------------- fused prep: cvt x, transpose W0/W1, count degrees (padded),
// zero a_s/a_d (both layers) + g, compute c = Wl^T b1 + bl ----

__global__ __launch_bounds__(256) void prep_k(const float* __restrict__ x,
                                              unsigned short* __restrict__ xb,
                                              const float* __restrict__ W0,
                                              unsigned short* __restrict__ WT0,
                                              const float* __restrict__ W1,
                                              unsigned short* __restrict__ WT1,
                                              const int* __restrict__ ei,
                                              int* __restrict__ degp,
                                              float* __restrict__ a_sd,
                                              const float* __restrict__ Wl,
                                              const float* __restrict__ b1,
                                              const float* __restrict__ bl,
                                              float* __restrict__ c2) {
    int b = blockIdx.x;
    if (b < PREP_CVT) {                       // x -> bf16 (float4 quads)
        int i = b * 256 + threadIdx.x;
        if (i < N_NODES * 128 / 4) {
            float4 v = *reinterpret_cast<const float4*>(x + (size_t)i * 4);
            ushort4 o;
            o.x = f2bf(v.x); o.y = f2bf(v.y); o.z = f2bf(v.z); o.w = f2bf(v.w);
            *reinterpret_cast<ushort4*>(xb + (size_t)i * 4) = o;
        }
        return;
    }
    b -= PREP_CVT;
    if (b < PREP_WT0) {                       // WT0[n][k] = bf16(W0[k][n]), K=128
        int idx = b * 256 + threadIdx.x;
        int k = idx >> 8, n = idx & 255;
        WT0[(size_t)n * 128 + k] = f2bf(W0[idx]);
        return;
    }
    b -= PREP_WT0;
    if (b < PREP_WT1) {                       // WT1[n][k] = bf16(W1[k][n]), K=256
        int idx = b * 256 + threadIdx.x;
        int k = idx >> 8, n = idx & 255;
        WT1[(size_t)n * 256 + k] = f2bf(W1[idx]);
        return;
    }
    b -= PREP_WT1;
    if (b < PREP_DEG) {                       // degree count (padded counters)
        int e = b * 256 + threadIdx.x;
        if (e < TOT_E) {
            int dst = (e < N_EDGES) ? ei[N_EDGES + e] : (e - N_EDGES);
            atomicAdd(&degp[dst << PADSH], 1);
        }
        return;
    }
    b -= PREP_DEG;
    if (b < PREP_ZERO) {                      // zero a_s/a_d (both layers) + g
        int i = b * 256 + threadIdx.x;
        if (i < N_NODES * 3)
            *reinterpret_cast<float4*>(a_sd + (size_t)i * 4) = make_float4(0, 0, 0, 0);
        return;
    }
    {                                         // c = Wl^T b1 + bl (one block)
        int k = threadIdx.x;                  // k in [0,256)
        int lane = k & 63;
        float bv = b1[k];
        float p0 = bv * Wl[k * 2 + 0];
        float p1 = bv * Wl[k * 2 + 1];
        if (k == 0) { p0 += bl[0]; p1 += bl[1]; }
#pragma unroll
        for (int off = 32; off; off >>= 1) {
            p0 += __shfl_xor(p0, off);
            p1 += __shfl_xor(p1, off);
        }
        if (lane == 0) {
            atomicAdd(&c2[0], p0);
            atomicAdd(&c2[1], p1);
        }
    }
}

// ---------------- CSR build ----------------

__global__ void offsets_k(const int* __restrict__ degp, int* __restrict__ start,
                          int* __restrict__ deg, int* __restrict__ cursorp,
                          int* __restrict__ total) {
    int lane = threadIdx.x & 63;
    int node = blockIdx.x * blockDim.x + threadIdx.x;
    int d = (node < N_NODES) ? degp[node << PADSH] : 0;
    int pre = d;
#pragma unroll
    for (int off = 1; off < 64; off <<= 1) {
        int v = __shfl_up(pre, off);
        if (lane >= off) pre += v;
    }
    int wtot = __shfl(pre, 63);
    int base = 0;
    if (lane == 63) base = atomicAdd(total, wtot);
    base = __shfl(base, 63);
    int my = base + pre - d;
    if (node < N_NODES) {
        start[node] = my;
        deg[node] = d;
        cursorp[node << PADSH] = my;
    }
}

__global__ void scatter_k(const int* __restrict__ ei, int* __restrict__ cursorp,
                          int* __restrict__ colv) {
    int e = blockIdx.x * blockDim.x + threadIdx.x;
    if (e >= TOT_E) return;
    int srcv, dstv;
    if (e < N_EDGES) { srcv = ei[e]; dstv = ei[N_EDGES + e]; }
    else             { srcv = dstv = e - N_EDGES; }
    int pos = atomicAdd(&cursorp[dstv << PADSH], 1);
    colv[pos] = srcv;
}

// ---------------- MFMA bf16 GEMM + fused attention epilogue ----------------
// LAST=false (layer 0): writes h16 bf16.
// LAST=true  (layer 1): NO h output; instead accumulates per-head final-linear
// projections g[row][head][0..1] = sum_{c in head} acc[c] * Wl[c][0..1].

template <int K, bool LAST>
__global__ __launch_bounds__(256) void mfma_gemm_att_k(
        const unsigned short* __restrict__ A,   // [M][K] bf16
        const unsigned short* __restrict__ BT,  // [256][K] bf16 (W transposed)
        unsigned short* __restrict__ h16,       // [M][256] bf16 out (LAST=false)
        const float* __restrict__ att_src, const float* __restrict__ att_dst,
        float* __restrict__ a_s, float* __restrict__ a_d, int M,
        const float* __restrict__ Wl, float* __restrict__ g) {
    const int bid = blockIdx.x;
    const int xcd = bid & 7;
    const int t   = bid >> 3;
    const int kx  = t & 3;
    const int gy  = xcd + 8 * (t >> 2);
    if (gy >= GY) return;

    const int lane = threadIdx.x & 63;
    const int wv = threadIdx.x >> 6;
    const int lm = lane & 15;
    const int g8 = (lane >> 4) * 8;
    const int row0 = gy * 128 + wv * 32;
    const int n0 = kx * 64;

    int ra0 = row0 + lm;       if (ra0 >= M) ra0 = M - 1;
    int ra1 = row0 + 16 + lm;  if (ra1 >= M) ra1 = M - 1;
    const unsigned short* pa0 = A + (size_t)ra0 * K + g8;
    const unsigned short* pa1 = A + (size_t)ra1 * K + g8;
    const unsigned short* pb  = BT + (size_t)(n0 + lm) * K + g8;

    f32x4 acc[2][4] = {};
#pragma unroll
    for (int kt = 0; kt < K; kt += 32) {
        bf16x8 a0 = *reinterpret_cast<const bf16x8*>(pa0 + kt);
        bf16x8 a1 = *reinterpret_cast<const bf16x8*>(pa1 + kt);
        bf16x8 b0 = *reinterpret_cast<const bf16x8*>(pb + kt);
        bf16x8 b1 = *reinterpret_cast<const bf16x8*>(pb + 16 * K + kt);
        bf16x8 b2 = *reinterpret_cast<const bf16x8*>(pb + 32 * K + kt);
        bf16x8 b3 = *reinterpret_cast<const bf16x8*>(pb + 48 * K + kt);
        acc[0][0] = __builtin_amdgcn_mfma_f32_16x16x32_bf16(a0, b0, acc[0][0], 0, 0, 0);
        acc[0][1] = __builtin_amdgcn_mfma_f32_16x16x32_bf16(a0, b1, acc[0][1], 0, 0, 0);
        acc[0][2] = __builtin_amdgcn_mfma_f32_16x16x32_bf16(a0, b2, acc[0][2], 0, 0, 0);
        acc[0][3] = __builtin_amdgcn_mfma_f32_16x16x32_bf16(a0, b3, acc[0][3], 0, 0, 0);
        acc[1][0] = __builtin_amdgcn_mfma_f32_16x16x32_bf16(a1, b0, acc[1][0], 0, 0, 0);
        acc[1][1] = __builtin_amdgcn_mfma_f32_16x16x32_bf16(a1, b1, acc[1][1], 0, 0, 0);
        acc[1][2] = __builtin_amdgcn_mfma_f32_16x16x32_bf16(a1, b2, acc[1][2], 0, 0, 0);
        acc[1][3] = __builtin_amdgcn_mfma_f32_16x16x32_bf16(a1, b3, acc[1][3], 0, 0, 0);
    }

    float as_c[4], ad_c[4], wl0_c[4], wl1_c[4];
#pragma unroll
    for (int j = 0; j < 4; ++j) {
        int c = n0 + j * 16 + lm;
        as_c[j] = att_src[c];
        ad_c[j] = att_dst[c];
        if (LAST) {
            wl0_c[j] = Wl[c * 2 + 0];
            wl1_c[j] = Wl[c * 2 + 1];
        }
    }
    const int head = n0 >> 7;

#pragma unroll
    for (int i = 0; i < 2; ++i) {
        float ps[4] = {}, pd[4] = {}, pg0[4] = {}, pg1[4] = {};
#pragma unroll
        for (int j = 0; j < 4; ++j)
#pragma unroll
            for (int r = 0; r < 4; ++r) {
                ps[r] += acc[i][j][r] * as_c[j];
                pd[r] += acc[i][j][r] * ad_c[j];
                if (LAST) {
                    pg0[r] += acc[i][j][r] * wl0_c[j];
                    pg1[r] += acc[i][j][r] * wl1_c[j];
                }
            }
#pragma unroll
        for (int off = 1; off < 16; off <<= 1)
#pragma unroll
            for (int r = 0; r < 4; ++r) {
                ps[r] += __shfl_xor(ps[r], off);
                pd[r] += __shfl_xor(pd[r], off);
                if (LAST) {
                    pg0[r] += __shfl_xor(pg0[r], off);
                    pg1[r] += __shfl_xor(pg1[r], off);
                }
            }
        if (lm == 0) {
            int rb = row0 + i * 16 + (lane >> 4) * 4;
#pragma unroll
            for (int r = 0; r < 4; ++r) {
                if (rb + r < M) {
                    atomicAdd(&a_s[(rb + r) * 2 + head], ps[r]);
                    atomicAdd(&a_d[(rb + r) * 2 + head], pd[r]);
                    if (LAST) {
                        atomicAdd(&g[(rb + r) * 4 + head * 2 + 0], pg0[r]);
                        atomicAdd(&g[(rb + r) * 4 + head * 2 + 1], pg1[r]);
                    }
                }
            }
        }
        if (!LAST) {
#pragma unroll
            for (int j = 0; j < 4; ++j)
#pragma unroll
                for (int r = 0; r < 4; ++r) {
                    int row = row0 + i * 16 + (lane >> 4) * 4 + r;
                    if (row < M)
                        h16[(size_t)row * HCv + n0 + j * 16 + lm] = f2bf(acc[i][j][r]);
                }
        }
    }
}

// ---------------- layer-0 aggregation (R12 body, unchanged) ----------------

__device__ __forceinline__ float lrelu(float x) { return x > 0.f ? x : 0.2f * x; }

__global__ __launch_bounds__(256) void agg_k(const unsigned short* __restrict__ h16,
                      const float* __restrict__ a_s, const float* __restrict__ a_d,
                      const int* __restrict__ start, const int* __restrict__ deg,
                      const int* __restrict__ colv, const float* __restrict__ bias,
                      unsigned short* __restrict__ out16) {
    __shared__ float lexp[4][MAXD][2];
    const int lane = threadIdx.x & 63;
    const int wslot = threadIdx.x >> 6;
    const int node = blockIdx.x * 4 + wslot;
    if (node >= N_NODES) return;
    const int beg = start[node];
    const int degv = deg[node];
    const float ad0 = a_d[node * 2], ad1 = a_d[node * 2 + 1];
    const int* __restrict__ col = colv + beg;

    if (degv <= MAXD) {
        float s0 = 0.f, s1 = 0.f;
        for (int j = lane; j < degv; j += 64) {
            int s = col[j];
            float2 av = *reinterpret_cast<const float2*>(a_s + s * 2);
            float e0 = __expf(lrelu(av.x + ad0));
            float e1 = __expf(lrelu(av.y + ad1));
            *reinterpret_cast<float2*>(&lexp[wslot][j][0]) = make_float2(e0, e1);
            s0 += e0;
            s1 += e1;
        }
#pragma unroll
        for (int off = 32; off; off >>= 1) {
            s0 += __shfl_xor(s0, off);
            s1 += __shfl_xor(s1, off);
        }
        const float inv0 = 1.f / (s0 + 1e-16f);
        const float inv1 = 1.f / (s1 + 1e-16f);

        const int q = lane >> 4;
        const int lq = lane & 15;
        const int cb = lq * 16;
        const int head = lq >> 3;
        const float invh = head ? inv1 : inv0;
        const unsigned short* __restrict__ hp = h16 + cb;
        f32x2 acc2[8] = {};
        const int full = degv >> 2;
        for (int i = 0; i < full; ++i) {
            const int j = 4 * i + q;
            const int s = col[j];
            const float alpha = lexp[wslot][j][head] * invh;
            const f32x2 al = {alpha, alpha};
            const uint4* p = reinterpret_cast<const uint4*>(hp + (size_t)s * HCv);
            const uint4 h0 = p[0];
            const uint4 h1 = p[1];
            fma_row8_pk(h0, al, acc2);
            fma_row8_pk(h1, al, acc2 + 4);
        }
        {
            const int j = full * 4 + q;
            if (j < degv) {
                const int s = col[j];
                const float alpha = lexp[wslot][j][head] * invh;
                const f32x2 al = {alpha, alpha};
                const uint4* p = reinterpret_cast<const uint4*>(hp + (size_t)s * HCv);
                const uint4 h0 = p[0];
                const uint4 h1 = p[1];
                fma_row8_pk(h0, al, acc2);
                fma_row8_pk(h1, al, acc2 + 4);
            }
        }
        float acc[16];
#pragma unroll
        for (int c = 0; c < 8; ++c) {
            acc[2 * c]     = acc2[c].x;
            acc[2 * c + 1] = acc2[c].y;
        }
#pragma unroll
        for (int c = 0; c < 16; ++c) {
            acc[c] += __shfl_xor(acc[c], 16);
            acc[c] += __shfl_xor(acc[c], 32);
        }
        if (lane < 16) {
#pragma unroll
            for (int c = 0; c < 16; ++c) acc[c] = tanhf(acc[c] + bias[cb + c]);
            uint4 v0, v1;
            v0.x = f2bf_pack(acc[0], acc[1]);
            v0.y = f2bf_pack(acc[2], acc[3]);
            v0.z = f2bf_pack(acc[4], acc[5]);
            v0.w = f2bf_pack(acc[6], acc[7]);
            v1.x = f2bf_pack(acc[8], acc[9]);
            v1.y = f2bf_pack(acc[10], acc[11]);
            v1.z = f2bf_pack(acc[12], acc[13]);
            v1.w = f2bf_pack(acc[14], acc[15]);
            uint4* o = reinterpret_cast<uint4*>(out16 + (size_t)node * HCv + cb);
            o[0] = v0;
            o[1] = v1;
        }
    } else {
        // fallback: 3-pass recompute path (deg > MAXD)
        const int end = beg + degv;
        float m0 = -INFINITY, m1 = -INFINITY;
        for (int e = beg + lane; e < end; e += 64) {
            int s = colv[e];
            m0 = fmaxf(m0, lrelu(a_s[s * 2] + ad0));
            m1 = fmaxf(m1, lrelu(a_s[s * 2 + 1] + ad1));
        }
#pragma unroll
        for (int off = 32; off; off >>= 1) {
            m0 = fmaxf(m0, __shfl_xor(m0, off));
            m1 = fmaxf(m1, __shfl_xor(m1, off));
        }
        float s0 = 0.f, s1 = 0.f;
        for (int e = beg + lane; e < end; e += 64) {
            int s = colv[e];
            s0 += __expf(lrelu(a_s[s * 2] + ad0) - m0);
            s1 += __expf(lrelu(a_s[s * 2 + 1] + ad1) - m1);
        }
#pragma unroll
        for (int off = 32; off; off >>= 1) {
            s0 += __shfl_xor(s0, off);
            s1 += __shfl_xor(s1, off);
        }
        float inv0 = 1.f / (s0 + 1e-16f);
        float inv1 = 1.f / (s1 + 1e-16f);
        const int head = lane >> 5;
        const float mh  = head ? m1 : m0;
        const float ih  = head ? inv1 : inv0;
        const float adh = head ? ad1 : ad0;
        const int cbase = lane * 4;
        float acc0 = 0.f, acc1 = 0.f, acc2 = 0.f, acc3 = 0.f;
        for (int e = beg; e < end; ++e) {
            int s = colv[e];
            float l = lrelu(a_s[s * 2 + head] + adh);
            float alpha = __expf(l - mh) * ih;
            uint2 hv = *reinterpret_cast<const uint2*>(h16 + (size_t)s * HCv + cbase);
            acc0 = fmaf(bf2f_lo(hv.x), alpha, acc0);
            acc1 = fmaf(bf2f_hi(hv.x), alpha, acc1);
            acc2 = fmaf(bf2f_lo(hv.y), alpha, acc2);
            acc3 = fmaf(bf2f_hi(hv.y), alpha, acc3);
        }
        float o0 = tanhf(acc0 + bias[cbase + 0]);
        float o1 = tanhf(acc1 + bias[cbase + 1]);
        float o2 = tanhf(acc2 + bias[cbase + 2]);
        float o3 = tanhf(acc3 + bias[cbase + 3]);
        ushort4 v;
        v.x = f2bf(o0); v.y = f2bf(o1); v.z = f2bf(o2); v.w = f2bf(o3);
        *reinterpret_cast<ushort4*>(out16 + (size_t)node * HCv + cbase) = v;
    }
}

// ---------------- layer-1 aggregation + final linear + softmax (pushdown) ----
// z[dst] = (sum e0*g0[src])/s0 + (sum e1*g1[src])/s1 + c;  out = softmax(z)

__global__ __launch_bounds__(256) void agg_final_k(
        const float* __restrict__ a_s, const float* __restrict__ a_d,
        const float* __restrict__ g, const int* __restrict__ start,
        const int* __restrict__ deg, const int* __restrict__ colv,
        const float* __restrict__ c2, float* __restrict__ out) {
    const int lane = threadIdx.x & 63;
    const int node = blockIdx.x * 4 + (threadIdx.x >> 6);
    if (node >= N_NODES) return;
    const int beg = start[node];
    const int degv = deg[node];
    const float ad0 = a_d[node * 2], ad1 = a_d[node * 2 + 1];
    const int* __restrict__ col = colv + beg;

    float s0 = 0.f, s1 = 0.f, A00 = 0.f, A01 = 0.f, A10 = 0.f, A11 = 0.f;
    for (int j = lane; j < degv; j += 64) {
        int s = col[j];
        float2 av = *reinterpret_cast<const float2*>(a_s + s * 2);
        float4 gv = *reinterpret_cast<const float4*>(g + s * 4);
        float e0 = __expf(lrelu(av.x + ad0));
        float e1 = __expf(lrelu(av.y + ad1));
        s0 += e0;
        s1 += e1;
        A00 = fmaf(e0, gv.x, A00);
        A01 = fmaf(e0, gv.y, A01);
        A10 = fmaf(e1, gv.z, A10);
        A11 = fmaf(e1, gv.w, A11);
    }
#pragma unroll
    for (int off = 32; off; off >>= 1) {
        s0  += __shfl_xor(s0, off);
        s1  += __shfl_xor(s1, off);
        A00 += __shfl_xor(A00, off);
        A01 += __shfl_xor(A01, off);
        A10 += __shfl_xor(A10, off);
        A11 += __shfl_xor(A11, off);
    }
    if (lane == 0) {
        float i0 = 1.f / (s0 + 1e-16f), i1 = 1.f / (s1 + 1e-16f);
        float z0 = A00 * i0 + A10 * i1 + c2[0];
        float z1 = A01 * i0 + A11 * i1 + c2[1];
        float mx = fmaxf(z0, z1);
        float e0 = __expf(z0 - mx), e1 = __expf(z1 - mx);
        float inv = 1.f / (e0 + e1);
        out[node * 2 + 0] = e0 * inv;
        out[node * 2 + 1] = e1 * inv;
    }
}

// ---------------- launch ----------------

extern "C" void kernel_launch(void* const* d_in, const int* in_sizes, int n_in,
                              void* d_out, int out_size, void* d_ws, size_t ws_size,
                              hipStream_t stream) {
    const float* x        = (const float*)d_in[0];
    const int*   ei       = (const int*)d_in[1];
    const float* W0       = (const float*)d_in[2];
    const float* att_src0 = (const float*)d_in[3];
    const float* att_dst0 = (const float*)d_in[4];
    const float* b0       = (const float*)d_in[5];
    const float* W1       = (const float*)d_in[6];
    const float* att_src1 = (const float*)d_in[7];
    const float* att_dst1 = (const float*)d_in[8];
    const float* b1       = (const float*)d_in[9];
    const float* Wl       = (const float*)d_in[10];
    const float* bl       = (const float*)d_in[11];
    float* out = (float*)d_out;

    // workspace layout
    unsigned short* xb     = (unsigned short*)d_ws;               // N*128 bf16
    unsigned short* h16    = xb + (size_t)N_NODES * 128;          // N*256 bf16 (layer0 gemm out)
    unsigned short* hact16 = h16 + (size_t)N_NODES * HCv;         // N*256 bf16 (layer0 agg out)
    unsigned short* WT0    = hact16 + (size_t)N_NODES * HCv;      // 256*128 bf16
    unsigned short* WT1    = WT0 + 256 * 128;                     // 256*256 bf16
    int*   degp  = (int*)(WT1 + 256 * 256);                       // N*32 (padded)
    float* a_sd  = (float*)(degp + (size_t)N_NODES * 32);         // N*12: as0 ad0 as1 ad1 g
    float* as0   = a_sd;
    float* ad0   = as0 + N_NODES * 2;
    float* as1   = ad0 + N_NODES * 2;
    float* ad1   = as1 + N_NODES * 2;
    float* gbuf  = ad1 + N_NODES * 2;                             // N*4
    int* cursorp = (int*)(gbuf + (size_t)N_NODES * 4);            // N*32 (padded)
    int* deg     = cursorp + (size_t)N_NODES * 32;                // N (compact)
    int* start   = deg + N_NODES;                                 // N
    int* total   = start + N_NODES;                               // 1
    float* c2    = (float*)(total + 1);                           // 2
    int* colv    = (int*)(c2 + 2);                                // E + N

    // ---- zero padded deg counters + total + c, then fused prep ----
    zero_degp_k<<<(N_NODES * 32 / 4 + 255) / 256, 256, 0, stream>>>((uint4*)degp,
                                                                    total, c2);
    prep_k<<<PREP_BLKS, 256, 0, stream>>>(x, xb, W0, WT0, W1, WT1, ei, degp, a_sd,
                                          Wl, b1, bl, c2);

    // ---- CSR offsets + scatter (padded cursors) ----
    offsets_k<<<(N_NODES + 255) / 256, 256, 0, stream>>>(degp, start, deg, cursorp, total);
    scatter_k<<<(TOT_E + 255) / 256, 256, 0, stream>>>(ei, cursorp, colv);

    int nn4 = (N_NODES + 3) / 4;

    // ---- layer 0 ----
    mfma_gemm_att_k<128, false><<<GEMM_BLKS, 256, 0, stream>>>(
        xb, WT0, h16, att_src0, att_dst0, as0, ad0, N_NODES, nullptr, nullptr);
    agg_k<<<nn4, 256, 0, stream>>>(h16, as0, ad0, start, deg, colv, b0, hact16);

    // ---- layer 1: GEMM computes attention coeffs + final-linear projections g;
    //      agg_final does the 8B/edge aggregation + softmax directly ----
    mfma_gemm_att_k<256, true><<<GEMM_BLKS, 256, 0, stream>>>(
        hact16, WT1, nullptr, att_src1, att_dst1, as1, ad1, N_NODES, Wl, gbuf);
    agg_final_k<<<nn4, 256, 0, stream>>>(as1, ad1, gbuf, start, deg, colv, c2, out);
}

// Round 14
// 295.601 us; speedup vs baseline: 1.1466x; 1.0685x over previous
//
#include <hip/hip_runtime.h>
#include <math.h>

// Problem constants (from reference)
constexpr int N_NODES = 50000;
constexpr int N_EDGES = 800000;
constexpr int TOT_E   = N_EDGES + N_NODES;   // + self loops
constexpr int HCv     = 256;                 // H*C
constexpr int MAXD    = 256;                 // LDS logit-cache capacity per wave

// GEMM grid geometry (XCD-swizzled 1-D launch; bid%8 == XCD round-robin)
constexpr int GY        = (N_NODES + 127) / 128;  // 391 row-tiles
constexpr int GPX       = (GY + 7) / 8;           // 49 row-tiles per XCD
constexpr int GEMM_BLKS = 8 * GPX * 4;            // 1568 (tail guarded)

// padded atomic counters: one int per 128B line (stride 32 ints)
constexpr int PADSH = 5;                          // <<5

// prep_k section sizes
constexpr int PREP_CVT   = (N_NODES * 128 / 4 + 255) / 256;   // 6250
constexpr int PREP_WT0   = 128;
constexpr int PREP_WT1   = 256;
constexpr int PREP_DEG   = (TOT_E + 255) / 256;               // 3321
constexpr int PREP_ZERO  = (N_NODES * 12 / 4 + 255) / 256;    // 587 (as0,ad0,as1,ad1,g)
constexpr int PREP_C     = 1;                                 // c = Wl^T b1 + bl
constexpr int PREP_BLKS  = PREP_CVT + PREP_WT0 + PREP_WT1 + PREP_DEG + PREP_ZERO + PREP_C;

typedef __attribute__((ext_vector_type(8))) short bf16x8;
typedef __attribute__((ext_vector_type(4))) float f32x4;
typedef __attribute__((ext_vector_type(2))) float f32x2;

// ---- bf16 helpers (manual RNE, deterministic) ----
__device__ __forceinline__ unsigned short f2bf(float f) {
    unsigned int u = __float_as_uint(f);
    unsigned int r = (u + 0x7fffu + ((u >> 16) & 1u)) >> 16;
    return (unsigned short)r;
}
__device__ __forceinline__ unsigned int f2bf_pack(float lo, float hi) {
    return (unsigned int)f2bf(lo) | ((unsigned int)f2bf(hi) << 16);
}
__device__ __forceinline__ float bf2f_lo(unsigned int packed) {
    return __uint_as_float(packed << 16);
}
__device__ __forceinline__ float bf2f_hi(unsigned int packed) {
    return __uint_as_float(packed & 0xffff0000u);
}

// 8 bf16 channels += alpha * row-fragment, packed f32x2
__device__ __forceinline__ void fma_row8_pk(const uint4 h, f32x2 al, f32x2* a2) {
    f32x2 p;
    p.x = bf2f_lo(h.x); p.y = bf2f_hi(h.x);
    a2[0] = __builtin_elementwise_fma(p, al, a2[0]);
    p.x = bf2f_lo(h.y); p.y = bf2f_hi(h.y);
    a2[1] = __builtin_elementwise_fma(p, al, a2[1]);
    p.x = bf2f_lo(h.z); p.y = bf2f_hi(h.z);
    a2[2] = __builtin_elementwise_fma(p, al, a2[2]);
    p.x = bf2f_lo(h.w); p.y = bf2f_hi(h.w);
    a2[3] = __builtin_elementwise_fma(p, al, a2[3]);
}

// ---------------- zero padded degree counters + total + c (runs before prep) ----

__global__ void zero_degp_k(uint4* __restrict__ degp4, int* __restrict__ total,
                            float* __restrict__ c2) {
    int i = blockIdx.x * blockDim.x + threadIdx.x;
    if (i < N_NODES * 32 / 4) degp4[i] = make_uint4(0, 0, 0, 0);
    if (blockIdx.x == 0 && threadIdx.x == 0) {
        *total = 0;
        c2[0] = 0.f;
        c2[1] = 0.f;
    }
}

// ---------------- fused prep: cvt x, transpose W0/W1, count degrees (padded),
// zero a_s/a_d (both layers) + g, compute c = Wl^T b1 + bl ----

__global__ __launch_bounds__(256) void prep_k(const float* __restrict__ x,
                                              unsigned short* __restrict__ xb,
                                              const float* __restrict__ W0,
                                              unsigned short* __restrict__ WT0,
                                              const float* __restrict__ W1,
                                              unsigned short* __restrict__ WT1,
                                              const int* __restrict__ ei,
                                              int* __restrict__ degp,
                                              float* __restrict__ a_sd,
                                              const float* __restrict__ Wl,
                                              const float* __restrict__ b1,
                                              const float* __restrict__ bl,
                                              float* __restrict__ c2) {
    int b = blockIdx.x;
    if (b < PREP_CVT) {                       // x -> bf16 (float4 quads)
        int i = b * 256 + threadIdx.x;
        if (i < N_NODES * 128 / 4) {
            float4 v = *reinterpret_cast<const float4*>(x + (size_t)i * 4);
            ushort4 o;
            o.x = f2bf(v.x); o.y = f2bf(v.y); o.z = f2bf(v.z); o.w = f2bf(v.w);
            *reinterpret_cast<ushort4*>(xb + (size_t)i * 4) = o;
        }
        return;
    }
    b -= PREP_CVT;
    if (b < PREP_WT0) {                       // WT0[n][k] = bf16(W0[k][n]), K=128
        int idx = b * 256 + threadIdx.x;
        int k = idx >> 8, n = idx & 255;
        WT0[(size_t)n * 128 + k] = f2bf(W0[idx]);
        return;
    }
    b -= PREP_WT0;
    if (b < PREP_WT1) {                       // WT1[n][k] = bf16(W1[k][n]), K=256
        int idx = b * 256 + threadIdx.x;
        int k = idx >> 8, n = idx & 255;
        WT1[(size_t)n * 256 + k] = f2bf(W1[idx]);
        return;
    }
    b -= PREP_WT1;
    if (b < PREP_DEG) {                       // degree count (padded counters)
        int e = b * 256 + threadIdx.x;
        if (e < TOT_E) {
            int dst = (e < N_EDGES) ? ei[N_EDGES + e] : (e - N_EDGES);
            atomicAdd(&degp[dst << PADSH], 1);
        }
        return;
    }
    b -= PREP_DEG;
    if (b < PREP_ZERO) {                      // zero a_s/a_d (both layers) + g
        int i = b * 256 + threadIdx.x;
        if (i < N_NODES * 3)
            *reinterpret_cast<float4*>(a_sd + (size_t)i * 4) = make_float4(0, 0, 0, 0);
        return;
    }
    {                                         // c = Wl^T b1 + bl (one block)
        int k = threadIdx.x;                  // k in [0,256)
        int lane = k & 63;
        float bv = b1[k];
        float p0 = bv * Wl[k * 2 + 0];
        float p1 = bv * Wl[k * 2 + 1];
        if (k == 0) { p0 += bl[0]; p1 += bl[1]; }
#pragma unroll
        for (int off = 32; off; off >>= 1) {
            p0 += __shfl_xor(p0, off);
            p1 += __shfl_xor(p1, off);
        }
        if (lane == 0) {
            atomicAdd(&c2[0], p0);
            atomicAdd(&c2[1], p1);
        }
    }
}

// ---------------- CSR build ----------------

__global__ void offsets_k(const int* __restrict__ degp, int* __restrict__ start,
                          int* __restrict__ deg, int* __restrict__ cursorp,
                          int* __restrict__ total) {
    int lane = threadIdx.x & 63;
    int node = blockIdx.x * blockDim.x + threadIdx.x;
    int d = (node < N_NODES) ? degp[node << PADSH] : 0;
    int pre = d;
#pragma unroll
    for (int off = 1; off < 64; off <<= 1) {
        int v = __shfl_up(pre, off);
        if (lane >= off) pre += v;
    }
    int wtot = __shfl(pre, 63);
    int base = 0;
    if (lane == 63) base = atomicAdd(total, wtot);
    base = __shfl(base, 63);
    int my = base + pre - d;
    if (node < N_NODES) {
        start[node] = my;
        deg[node] = d;
        cursorp[node << PADSH] = my;
    }
}

__global__ void scatter_k(const int* __restrict__ ei, int* __restrict__ cursorp,
                          int* __restrict__ colv) {
    int e = blockIdx.x * blockDim.x + threadIdx.x;
    if (e >= TOT_E) return;
    int srcv, dstv;
    if (e < N_EDGES) { srcv = ei[e]; dstv = ei[N_EDGES + e]; }
    else             { srcv = dstv = e - N_EDGES; }
    int pos = atomicAdd(&cursorp[dstv << PADSH], 1);
    colv[pos] = srcv;
}

// ---------------- MFMA bf16 GEMM + fused attention epilogue ----------------
// LAST=false (layer 0): writes h16 bf16.
// LAST=true  (layer 1): NO h output; instead accumulates per-head final-linear
// projections g[row][head][0..1] = sum_{c in head} acc[c] * Wl[c][0..1].

template <int K, bool LAST>
__global__ __launch_bounds__(256) void mfma_gemm_att_k(
        const unsigned short* __restrict__ A,   // [M][K] bf16
        const unsigned short* __restrict__ BT,  // [256][K] bf16 (W transposed)
        unsigned short* __restrict__ h16,       // [M][256] bf16 out (LAST=false)
        const float* __restrict__ att_src, const float* __restrict__ att_dst,
        float* __restrict__ a_s, float* __restrict__ a_d, int M,
        const float* __restrict__ Wl, float* __restrict__ g) {
    const int bid = blockIdx.x;
    const int xcd = bid & 7;
    const int t   = bid >> 3;
    const int kx  = t & 3;
    const int gy  = xcd + 8 * (t >> 2);
    if (gy >= GY) return;

    const int lane = threadIdx.x & 63;
    const int wv = threadIdx.x >> 6;
    const int lm = lane & 15;
    const int g8 = (lane >> 4) * 8;
    const int row0 = gy * 128 + wv * 32;
    const int n0 = kx * 64;

    int ra0 = row0 + lm;       if (ra0 >= M) ra0 = M - 1;
    int ra1 = row0 + 16 + lm;  if (ra1 >= M) ra1 = M - 1;
    const unsigned short* pa0 = A + (size_t)ra0 * K + g8;
    const unsigned short* pa1 = A + (size_t)ra1 * K + g8;
    const unsigned short* pb  = BT + (size_t)(n0 + lm) * K + g8;

    f32x4 acc[2][4] = {};
#pragma unroll
    for (int kt = 0; kt < K; kt += 32) {
        bf16x8 a0 = *reinterpret_cast<const bf16x8*>(pa0 + kt);
        bf16x8 a1 = *reinterpret_cast<const bf16x8*>(pa1 + kt);
        bf16x8 b0 = *reinterpret_cast<const bf16x8*>(pb + kt);
        bf16x8 b1 = *reinterpret_cast<const bf16x8*>(pb + 16 * K + kt);
        bf16x8 b2 = *reinterpret_cast<const bf16x8*>(pb + 32 * K + kt);
        bf16x8 b3 = *reinterpret_cast<const bf16x8*>(pb + 48 * K + kt);
        acc[0][0] = __builtin_amdgcn_mfma_f32_16x16x32_bf16(a0, b0, acc[0][0], 0, 0, 0);
        acc[0][1] = __builtin_amdgcn_mfma_f32_16x16x32_bf16(a0, b1, acc[0][1], 0, 0, 0);
        acc[0][2] = __builtin_amdgcn_mfma_f32_16x16x32_bf16(a0, b2, acc[0][2], 0, 0, 0);
        acc[0][3] = __builtin_amdgcn_mfma_f32_16x16x32_bf16(a0, b3, acc[0][3], 0, 0, 0);
        acc[1][0] = __builtin_amdgcn_mfma_f32_16x16x32_bf16(a1, b0, acc[1][0], 0, 0, 0);
        acc[1][1] = __builtin_amdgcn_mfma_f32_16x16x32_bf16(a1, b1, acc[1][1], 0, 0, 0);
        acc[1][2] = __builtin_amdgcn_mfma_f32_16x16x32_bf16(a1, b2, acc[1][2], 0, 0, 0);
        acc[1][3] = __builtin_amdgcn_mfma_f32_16x16x32_bf16(a1, b3, acc[1][3], 0, 0, 0);
    }

    float as_c[4], ad_c[4], wl0_c[4], wl1_c[4];
#pragma unroll
    for (int j = 0; j < 4; ++j) {
        int c = n0 + j * 16 + lm;
        as_c[j] = att_src[c];
        ad_c[j] = att_dst[c];
        if (LAST) {
            wl0_c[j] = Wl[c * 2 + 0];
            wl1_c[j] = Wl[c * 2 + 1];
        }
    }
    const int head = n0 >> 7;

#pragma unroll
    for (int i = 0; i < 2; ++i) {
        float ps[4] = {}, pd[4] = {}, pg0[4] = {}, pg1[4] = {};
#pragma unroll
        for (int j = 0; j < 4; ++j)
#pragma unroll
            for (int r = 0; r < 4; ++r) {
                ps[r] += acc[i][j][r] * as_c[j];
                pd[r] += acc[i][j][r] * ad_c[j];
                if (LAST) {
                    pg0[r] += acc[i][j][r] * wl0_c[j];
                    pg1[r] += acc[i][j][r] * wl1_c[j];
                }
            }
#pragma unroll
        for (int off = 1; off < 16; off <<= 1)
#pragma unroll
            for (int r = 0; r < 4; ++r) {
                ps[r] += __shfl_xor(ps[r], off);
                pd[r] += __shfl_xor(pd[r], off);
                if (LAST) {
                    pg0[r] += __shfl_xor(pg0[r], off);
                    pg1[r] += __shfl_xor(pg1[r], off);
                }
            }
        if (lm == 0) {
            int rb = row0 + i * 16 + (lane >> 4) * 4;
#pragma unroll
            for (int r = 0; r < 4; ++r) {
                if (rb + r < M) {
                    atomicAdd(&a_s[(rb + r) * 2 + head], ps[r]);
                    atomicAdd(&a_d[(rb + r) * 2 + head], pd[r]);
                    if (LAST) {
                        atomicAdd(&g[(rb + r) * 4 + head * 2 + 0], pg0[r]);
                        atomicAdd(&g[(rb + r) * 4 + head * 2 + 1], pg1[r]);
                    }
                }
            }
        }
        if (!LAST) {
#pragma unroll
            for (int j = 0; j < 4; ++j)
#pragma unroll
                for (int r = 0; r < 4; ++r) {
                    int row = row0 + i * 16 + (lane >> 4) * 4 + r;
                    if (row < M)
                        h16[(size_t)row * HCv + n0 + j * 16 + lm] = f2bf(acc[i][j][r]);
                }
        }
    }
}

// ---------------- layer-0 aggregation (R12-exact templated body) ----------------

__device__ __forceinline__ float lrelu(float x) { return x > 0.f ? x : 0.2f * x; }

template <bool TANH>
__global__ __launch_bounds__(256) void agg_k(const unsigned short* __restrict__ h16,
                      const float* __restrict__ a_s, const float* __restrict__ a_d,
                      const int* __restrict__ start, const int* __restrict__ deg,
                      const int* __restrict__ colv, const float* __restrict__ bias,
                      unsigned short* __restrict__ out16) {
    __shared__ float lexp[4][MAXD][2];
    const int lane = threadIdx.x & 63;
    const int wslot = threadIdx.x >> 6;
    const int node = blockIdx.x * 4 + wslot;
    if (node >= N_NODES) return;
    const int beg = start[node];
    const int degv = deg[node];
    const float ad0 = a_d[node * 2], ad1 = a_d[node * 2 + 1];
    const int* __restrict__ col = colv + beg;

    if (degv <= MAXD) {
        // ---- pass A: gather a_s, exp (max-free), stash to LDS, sum ----
        float s0 = 0.f, s1 = 0.f;
        for (int j = lane; j < degv; j += 64) {
            int s = col[j];
            float2 av = *reinterpret_cast<const float2*>(a_s + s * 2);
            float e0 = __expf(lrelu(av.x + ad0));
            float e1 = __expf(lrelu(av.y + ad1));
            *reinterpret_cast<float2*>(&lexp[wslot][j][0]) = make_float2(e0, e1);
            s0 += e0;
            s1 += e1;
        }
#pragma unroll
        for (int off = 32; off; off >>= 1) {
            s0 += __shfl_xor(s0, off);
            s1 += __shfl_xor(s1, off);
        }
        const float inv0 = 1.f / (s0 + 1e-16f);
        const float inv1 = 1.f / (s1 + 1e-16f);

        // ---- pass B: 4 edges/iter; quarter q owns edge 4i+q; lane covers
        // 16 channels [lq*16, lq*16+16); packed f32x2 accumulate ----
        const int q = lane >> 4;
        const int lq = lane & 15;
        const int cb = lq * 16;
        const int head = lq >> 3;
        const float invh = head ? inv1 : inv0;
        const unsigned short* __restrict__ hp = h16 + cb;
        f32x2 acc2[8] = {};
        const int full = degv >> 2;
        for (int i = 0; i < full; ++i) {
            const int j = 4 * i + q;
            const int s = col[j];
            const float alpha = lexp[wslot][j][head] * invh;
            const f32x2 al = {alpha, alpha};
            const uint4* p = reinterpret_cast<const uint4*>(hp + (size_t)s * HCv);
            const uint4 h0 = p[0];
            const uint4 h1 = p[1];
            fma_row8_pk(h0, al, acc2);
            fma_row8_pk(h1, al, acc2 + 4);
        }
        {   // tail (degv & 3 edges)
            const int j = full * 4 + q;
            if (j < degv) {
                const int s = col[j];
                const float alpha = lexp[wslot][j][head] * invh;
                const f32x2 al = {alpha, alpha};
                const uint4* p = reinterpret_cast<const uint4*>(hp + (size_t)s * HCv);
                const uint4 h0 = p[0];
                const uint4 h1 = p[1];
                fma_row8_pk(h0, al, acc2);
                fma_row8_pk(h1, al, acc2 + 4);
            }
        }
        float acc[16];
#pragma unroll
        for (int c = 0; c < 8; ++c) {
            acc[2 * c]     = acc2[c].x;
            acc[2 * c + 1] = acc2[c].y;
        }
#pragma unroll
        for (int c = 0; c < 16; ++c) {
            acc[c] += __shfl_xor(acc[c], 16);
            acc[c] += __shfl_xor(acc[c], 32);
        }
        if (lane < 16) {
#pragma unroll
            for (int c = 0; c < 16; ++c) acc[c] += bias[cb + c];
            if (TANH) {
#pragma unroll
                for (int c = 0; c < 16; ++c) acc[c] = tanhf(acc[c]);
            }
            uint4 v0, v1;
            v0.x = f2bf_pack(acc[0], acc[1]);
            v0.y = f2bf_pack(acc[2], acc[3]);
            v0.z = f2bf_pack(acc[4], acc[5]);
            v0.w = f2bf_pack(acc[6], acc[7]);
            v1.x = f2bf_pack(acc[8], acc[9]);
            v1.y = f2bf_pack(acc[10], acc[11]);
            v1.z = f2bf_pack(acc[12], acc[13]);
            v1.w = f2bf_pack(acc[14], acc[15]);
            uint4* o = reinterpret_cast<uint4*>(out16 + (size_t)node * HCv + cb);
            o[0] = v0;
            o[1] = v1;
        }
    } else {
        // ---- fallback: 3-pass recompute path (deg > MAXD) ----
        const int end = beg + degv;
        float m0 = -INFINITY, m1 = -INFINITY;
        for (int e = beg + lane; e < end; e += 64) {
            int s = colv[e];
            m0 = fmaxf(m0, lrelu(a_s[s * 2] + ad0));
            m1 = fmaxf(m1, lrelu(a_s[s * 2 + 1] + ad1));
        }
#pragma unroll
        for (int off = 32; off; off >>= 1) {
            m0 = fmaxf(m0, __shfl_xor(m0, off));
            m1 = fmaxf(m1, __shfl_xor(m1, off));
        }
        float s0 = 0.f, s1 = 0.f;
        for (int e = beg + lane; e < end; e += 64) {
            int s = colv[e];
            s0 += __expf(lrelu(a_s[s * 2] + ad0) - m0);
            s1 += __expf(lrelu(a_s[s * 2 + 1] + ad1) - m1);
        }
#pragma unroll
        for (int off = 32; off; off >>= 1) {
            s0 += __shfl_xor(s0, off);
            s1 += __shfl_xor(s1, off);
        }
        float inv0 = 1.f / (s0 + 1e-16f);
        float inv1 = 1.f / (s1 + 1e-16f);
        const int head = lane >> 5;
        const float mh  = head ? m1 : m0;
        const float ih  = head ? inv1 : inv0;
        const float adh = head ? ad1 : ad0;
        const int cbase = lane * 4;
        float acc0 = 0.f, acc1 = 0.f, acc2 = 0.f, acc3 = 0.f;
        for (int e = beg; e < end; ++e) {
            int s = colv[e];
            float l = lrelu(a_s[s * 2 + head] + adh);
            float alpha = __expf(l - mh) * ih;
            uint2 hv = *reinterpret_cast<const uint2*>(h16 + (size_t)s * HCv + cbase);
            acc0 = fmaf(bf2f_lo(hv.x), alpha, acc0);
            acc1 = fmaf(bf2f_hi(hv.x), alpha, acc1);
            acc2 = fmaf(bf2f_lo(hv.y), alpha, acc2);
            acc3 = fmaf(bf2f_hi(hv.y), alpha, acc3);
        }
        float o0 = acc0 + bias[cbase + 0];
        float o1 = acc1 + bias[cbase + 1];
        float o2 = acc2 + bias[cbase + 2];
        float o3 = acc3 + bias[cbase + 3];
        if (TANH) {
            o0 = tanhf(o0); o1 = tanhf(o1); o2 = tanhf(o2); o3 = tanhf(o3);
        }
        ushort4 v;
        v.x = f2bf(o0); v.y = f2bf(o1); v.z = f2bf(o2); v.w = f2bf(o3);
        *reinterpret_cast<ushort4*>(out16 + (size_t)node * HCv + cbase) = v;
    }
}

// ---------------- layer-1 aggregation + final linear + softmax (pushdown) ----
// z[dst] = (sum e0*g0[src])/s0 + (sum e1*g1[src])/s1 + c;  out = softmax(z)

__global__ __launch_bounds__(256) void agg_final_k(
        const float* __restrict__ a_s, const float* __restrict__ a_d,
        const float* __restrict__ g, const int* __restrict__ start,
        const int* __restrict__ deg, const int* __restrict__ colv,
        const float* __restrict__ c2, float* __restrict__ out) {
    const int lane = threadIdx.x & 63;
    const int node = blockIdx.x * 4 + (threadIdx.x >> 6);
    if (node >= N_NODES) return;
    const int beg = start[node];
    const int degv = deg[node];
    const float ad0 = a_d[node * 2], ad1 = a_d[node * 2 + 1];
    const int* __restrict__ col = colv + beg;

    float s0 = 0.f, s1 = 0.f, A00 = 0.f, A01 = 0.f, A10 = 0.f, A11 = 0.f;
    for (int j = lane; j < degv; j += 64) {
        int s = col[j];
        float2 av = *reinterpret_cast<const float2*>(a_s + s * 2);
        float4 gv = *reinterpret_cast<const float4*>(g + s * 4);
        float e0 = __expf(lrelu(av.x + ad0));
        float e1 = __expf(lrelu(av.y + ad1));
        s0 += e0;
        s1 += e1;
        A00 = fmaf(e0, gv.x, A00);
        A01 = fmaf(e0, gv.y, A01);
        A10 = fmaf(e1, gv.z, A10);
        A11 = fmaf(e1, gv.w, A11);
    }
#pragma unroll
    for (int off = 32; off; off >>= 1) {
        s0  += __shfl_xor(s0, off);
        s1  += __shfl_xor(s1, off);
        A00 += __shfl_xor(A00, off);
        A01 += __shfl_xor(A01, off);
        A10 += __shfl_xor(A10, off);
        A11 += __shfl_xor(A11, off);
    }
    if (lane == 0) {
        float i0 = 1.f / (s0 + 1e-16f), i1 = 1.f / (s1 + 1e-16f);
        float z0 = A00 * i0 + A10 * i1 + c2[0];
        float z1 = A01 * i0 + A11 * i1 + c2[1];
        float mx = fmaxf(z0, z1);
        float e0 = __expf(z0 - mx), e1 = __expf(z1 - mx);
        float inv = 1.f / (e0 + e1);
        out[node * 2 + 0] = e0 * inv;
        out[node * 2 + 1] = e1 * inv;
    }
}

// ---------------- launch ----------------

extern "C" void kernel_launch(void* const* d_in, const int* in_sizes, int n_in,
                              void* d_out, int out_size, void* d_ws, size_t ws_size,
                              hipStream_t stream) {
    const float* x        = (const float*)d_in[0];
    const int*   ei       = (const int*)d_in[1];
    const float* W0       = (const float*)d_in[2];
    const float* att_src0 = (const float*)d_in[3];
    const float* att_dst0 = (const float*)d_in[4];
    const float* b0       = (const float*)d_in[5];
    const float* W1       = (const float*)d_in[6];
    const float* att_src1 = (const float*)d_in[7];
    const float* att_dst1 = (const float*)d_in[8];
    const float* b1       = (const float*)d_in[9];
    const float* Wl       = (const float*)d_in[10];
    const float* bl       = (const float*)d_in[11];
    float* out = (float*)d_out;

    // workspace layout
    unsigned short* xb     = (unsigned short*)d_ws;               // N*128 bf16
    unsigned short* h16    = xb + (size_t)N_NODES * 128;          // N*256 bf16 (layer0 gemm out)
    unsigned short* hact16 = h16 + (size_t)N_NODES * HCv;         // N*256 bf16 (layer0 agg out)
    unsigned short* WT0    = hact16 + (size_t)N_NODES * HCv;      // 256*128 bf16
    unsigned short* WT1    = WT0 + 256 * 128;                     // 256*256 bf16
    int*   degp  = (int*)(WT1 + 256 * 256);                       // N*32 (padded)
    float* a_sd  = (float*)(degp + (size_t)N_NODES * 32);         // N*12: as0 ad0 as1 ad1 g
    float* as0   = a_sd;
    float* ad0   = as0 + N_NODES * 2;
    float* as1   = ad0 + N_NODES * 2;
    float* ad1   = as1 + N_NODES * 2;
    float* gbuf  = ad1 + N_NODES * 2;                             // N*4
    int* cursorp = (int*)(gbuf + (size_t)N_NODES * 4);            // N*32 (padded)
    int* deg     = cursorp + (size_t)N_NODES * 32;                // N (compact)
    int* start   = deg + N_NODES;                                 // N
    int* total   = start + N_NODES;                               // 1
    float* c2    = (float*)(total + 1);                           // 2
    int* colv    = (int*)(c2 + 2);                                // E + N

    // ---- zero padded deg counters + total + c, then fused prep ----
    zero_degp_k<<<(N_NODES * 32 / 4 + 255) / 256, 256, 0, stream>>>((uint4*)degp,
                                                                    total, c2);
    prep_k<<<PREP_BLKS, 256, 0, stream>>>(x, xb, W0, WT0, W1, WT1, ei, degp, a_sd,
                                          Wl, b1, bl, c2);

    // ---- CSR offsets + scatter (padded cursors) ----
    offsets_k<<<(N_NODES + 255) / 256, 256, 0, stream>>>(degp, start, deg, cursorp, total);
    scatter_k<<<(TOT_E + 255) / 256, 256, 0, stream>>>(ei, cursorp, colv);

    int nn4 = (N_NODES + 3) / 4;

    // ---- layer 0 ----
    mfma_gemm_att_k<128, false><<<GEMM_BLKS, 256, 0, stream>>>(
        xb, WT0, h16, att_src0, att_dst0, as0, ad0, N_NODES, nullptr, nullptr);
    agg_k<true><<<nn4, 256, 0, stream>>>(h16, as0, ad0, start, deg, colv, b0, hact16);

    // ---- layer 1: GEMM computes attention coeffs + final-linear projections g;
    //      agg_final does the 8B/edge aggregation + softmax directly ----
    mfma_gemm_att_k<256, true><<<GEMM_BLKS, 256, 0, stream>>>(
        hact16, WT1, nullptr, att_src1, att_dst1, as1, ad1, N_NODES, Wl, gbuf);
    agg_final_k<<<nn4, 256, 0, stream>>>(as1, ad1, gbuf, start, deg, colv, c2, out);
}